// Round 8
// baseline (258.219 us; speedup 1.0000x reference)
//
#include <hip/hip_runtime.h>
#include <hip/hip_bf16.h>
#include <math.h>

#define D_MODEL 1024
#define HS 2048
#define HE 1024
#define NEXP 8
#define NTOK 4096
#define NSLOT 8192

typedef __attribute__((ext_vector_type(4))) float f32x4;
typedef __attribute__((ext_vector_type(8))) short bf16x8;

__device__ __forceinline__ short f2b(float f) {
  __hip_bfloat16 h = __float2bfloat16(f);
  return *reinterpret_cast<short*>(&h);
}
__device__ __forceinline__ float b2f(short s) {
  return __bfloat162float(*reinterpret_cast<__hip_bfloat16*>(&s));
}

__device__ __forceinline__ void gl_lds16(const short* g, short* l) {
  __builtin_amdgcn_global_load_lds(
      (const __attribute__((address_space(1))) void*)g,
      (__attribute__((address_space(3))) void*)l, 16, 0, 0);
}

// ---------------- converts ----------------
__global__ __launch_bounds__(256) void cvt_x_kernel(const float* __restrict__ in,
                                                    short* __restrict__ out) {
  int i = blockIdx.x * 256 + threadIdx.x;  // over NTOK*D/4
  const float4 v = ((const float4*)in)[i];
  short4 o;
  o.x = f2b(v.x); o.y = f2b(v.y); o.z = f2b(v.z); o.w = f2b(v.w);
  ((short4*)out)[i] = o;
}

// in [R][C] f32 -> out bf16 transposed. RMAP: 0 plain [C][R]; 1/2: w13I
// interleaved row remap: out_row = (c>>5)*64 + (RMAP==2?32:0) + (c&31).
template <int RMAP>
__global__ __launch_bounds__(256) void transpose_cvt(const float* __restrict__ in,
                                                     short* __restrict__ out,
                                                     int R, int C) {
  __shared__ float tile[64][69];  // tile[col][row]
  const int t = threadIdx.x;
  const int c0 = blockIdx.x * 64;
  const int r0 = blockIdx.y * 64;
  const size_t bo = (size_t)blockIdx.z * R * C;
  const int lr = t >> 4;          // 0..15
  const int lc4 = (t & 15) * 4;   // 0..60
#pragma unroll
  for (int i = 0; i < 4; i++) {
    const float4 v = *(const float4*)&in[bo + (size_t)(r0 + lr + i * 16) * C + c0 + lc4];
    tile[lc4 + 0][lr + i * 16] = v.x;
    tile[lc4 + 1][lr + i * 16] = v.y;
    tile[lc4 + 2][lr + i * 16] = v.z;
    tile[lc4 + 3][lr + i * 16] = v.w;
  }
  __syncthreads();
#pragma unroll
  for (int i = 0; i < 4; i++) {
    const int oc = (t >> 4) + i * 16;  // local out row (= in col)
    const int or4 = (t & 15) * 4;      // local out col (= in row)
    short4 o;
    o.x = f2b(tile[oc][or4 + 0]);
    o.y = f2b(tile[oc][or4 + 1]);
    o.z = f2b(tile[oc][or4 + 2]);
    o.w = f2b(tile[oc][or4 + 3]);
    const int c = c0 + oc;
    size_t orow;
    if (RMAP == 0) orow = bo + (size_t)c * R;
    else orow = (size_t)((c >> 5) * 64 + (RMAP == 2 ? 32 : 0) + (c & 31)) * R;
    *(short4*)&out[orow + r0 + or4] = o;
  }
}

// ---------------- router (wave per token, float4) ----------------
__global__ __launch_bounds__(256) void router_kernel(
    const float* __restrict__ x, const float* __restrict__ temb,
    const float* __restrict__ rw, const float* __restrict__ rbias,
    int* __restrict__ topk, float* __restrict__ gates) {
  const int t = (blockIdx.x * 256 + threadIdx.x) >> 6;
  const int lane = threadIdx.x & 63;
  const float* xr = x + (size_t)t * D_MODEL;
  const float* tr = temb + (size_t)(t >> 10) * D_MODEL;  // T=1024
  float acc[NEXP] = {};
#pragma unroll
  for (int i = 0; i < 4; i++) {
    const int j = i * 256 + lane * 4;
    const float4 xv = *(const float4*)&xr[j];
    const float4 tv = *(const float4*)&tr[j];
    const float* wx = rw + (size_t)j * NEXP;
    const float* wt = rw + (size_t)(D_MODEL + j) * NEXP;
    const float xa[4] = {xv.x, xv.y, xv.z, xv.w};
    const float ta[4] = {tv.x, tv.y, tv.z, tv.w};
#pragma unroll
    for (int u = 0; u < 4; u++)
#pragma unroll
      for (int e = 0; e < NEXP; e++)
        acc[e] += xa[u] * wx[u * NEXP + e] + ta[u] * wt[u * NEXP + e];
  }
#pragma unroll
  for (int off = 32; off; off >>= 1)
#pragma unroll
    for (int e = 0; e < NEXP; e++) acc[e] += __shfl_xor(acc[e], off);
  if (lane == 0) {
    float s[NEXP], sel[NEXP];
#pragma unroll
    for (int e = 0; e < NEXP; e++) {
      s[e] = 1.f / (1.f + expf(-acc[e]));
      sel[e] = s[e] + rbias[e];
    }
    int i0 = 0;
#pragma unroll
    for (int e = 1; e < NEXP; e++) if (sel[e] > sel[i0]) i0 = e;
    int i1 = (i0 == 0) ? 1 : 0;
#pragma unroll
    for (int e = 0; e < NEXP; e++) if (e != i0 && sel[e] > sel[i1]) i1 = e;
    float s0 = s[i0], s1 = s[i1], den = s0 + s1;
    float g0, g1;
    if (den > 1e-9f) { g0 = s0 / (den + 1e-9f); g1 = s1 / (den + 1e-9f); }
    else { g0 = 0.5f; g1 = 0.5f; }
    topk[t * 2] = i0; topk[t * 2 + 1] = i1;
    gates[t * 2] = g0; gates[t * 2 + 1] = g1;
  }
}

// ------- grouping: hist + scan + fill + COMPACT TILE TABLE in one block ------
// te/tm: per-tile (expert, m0) for BM=128 tiles; ntile <= 71.
__global__ __launch_bounds__(1024) void group_kernel(const int* __restrict__ topk,
                                                     int* __restrict__ perm,
                                                     int* __restrict__ offs,
                                                     int* __restrict__ te,
                                                     int* __restrict__ tm,
                                                     int* __restrict__ ntile) {
  __shared__ int cnt[NEXP], cur[NEXP];
  const int t = threadIdx.x;
  if (t < NEXP) cnt[t] = 0;
  __syncthreads();
  int mye[8];
#pragma unroll
  for (int i = 0; i < 8; i++) {
    mye[i] = topk[i * 1024 + t];
    atomicAdd(&cnt[mye[i]], 1);
  }
  __syncthreads();
  if (t == 0) {
    int a = 0;
    for (int e = 0; e < NEXP; e++) { offs[e] = a; cur[e] = a; a += cnt[e]; }
    offs[NEXP] = a;
    int nt = 0;
    for (int e = 0; e < NEXP; e++)
      for (int m0 = 0; m0 < cnt[e]; m0 += 128) { te[nt] = e; tm[nt] = m0; nt++; }
    ntile[0] = nt;
  }
  __syncthreads();
#pragma unroll
  for (int i = 0; i < 8; i++) {
    int pos = atomicAdd(&cur[mye[i]], 1);
    perm[pos] = i * 1024 + t;
  }
}

// ========== G1: 256x256 BK=64 per-phase-barrier 8-wave (R5-proven) ==========
__global__ __launch_bounds__(512, 1) void gemm_g1_8ph(
    const short* __restrict__ A, const short* __restrict__ B, short* __restrict__ U) {
  extern __shared__ short lds[];
  const int td = threadIdx.x;
  const int bx = blockIdx.x;
  const int m0 = blockIdx.y * 256;
  const short* Bbase = B + (size_t)bx * 256 * 1024;

  const int srow = td >> 3;
  const int colsw8 = ((td & 7) ^ (srow & 7)) * 8;
  const short* ap[2][2];
  const short* bp[2][2];
#pragma unroll
  for (int h = 0; h < 2; h++)
#pragma unroll
    for (int i = 0; i < 2; i++) {
      const int trow = h * 128 + i * 64 + srow;
      ap[h][i] = A + (size_t)(m0 + trow) * 1024 + colsw8;
      bp[h][i] = Bbase + (size_t)trow * 1024 + colsw8;
    }

#define SB0(t_, b_)                                                        \
  do {                                                                     \
    gl_lds16(bp[0][0] + (t_) * 64, lds + (b_) * 32768 + 16384 + td * 8);   \
    gl_lds16(bp[0][1] + (t_) * 64, lds + (b_) * 32768 + 16384 + 4096 + td * 8); \
  } while (0)
#define SB1(t_, b_)                                                        \
  do {                                                                     \
    gl_lds16(bp[1][0] + (t_) * 64, lds + (b_) * 32768 + 16384 + 8192 + td * 8); \
    gl_lds16(bp[1][1] + (t_) * 64, lds + (b_) * 32768 + 16384 + 8192 + 4096 + td * 8); \
  } while (0)
#define SAI0(t_, b_)                                                       \
  do {                                                                     \
    gl_lds16(ap[0][0] + (t_) * 64, lds + (b_) * 32768 + td * 8);           \
    gl_lds16(ap[1][0] + (t_) * 64, lds + (b_) * 32768 + 8192 + td * 8);    \
  } while (0)
#define SAI1(t_, b_)                                                       \
  do {                                                                     \
    gl_lds16(ap[0][1] + (t_) * 64, lds + (b_) * 32768 + 4096 + td * 8);    \
    gl_lds16(ap[1][1] + (t_) * 64, lds + (b_) * 32768 + 8192 + 4096 + td * 8); \
  } while (0)

  const int l = td & 63;
  const int wid = td >> 6;
  const int mh = wid >> 2;
  const int wn4 = wid & 3;
  const int lr = l & 15;
  const int bhsel = wn4 >> 1;
  const int bnr = (wn4 & 1) * 64;
  const int swzk0 = ((0 + (l >> 4) * 16) ^ ((l & 7) << 4)) >> 1;
  const int swzk1 = ((64 + (l >> 4) * 16) ^ ((l & 7) << 4)) >> 1;

#define LDA(mf_, swz_) (*(const bf16x8*)&Ah[(unsigned)(((mf_)*16 + lr) * 64) + (swz_)])
#define LDB(nf_, swz_) (*(const bf16x8*)&Bh[(unsigned)((bnr + (nf_)*16 + lr) * 64) + (swz_)])
#define MMROW(mf_, a_)                                                                 \
  acc[mf_][0] = __builtin_amdgcn_mfma_f32_16x16x32_bf16(a_, b0, acc[mf_][0], 0, 0, 0); \
  acc[mf_][1] = __builtin_amdgcn_mfma_f32_16x16x32_bf16(a_, b1, acc[mf_][1], 0, 0, 0); \
  acc[mf_][2] = __builtin_amdgcn_mfma_f32_16x16x32_bf16(a_, b2, acc[mf_][2], 0, 0, 0); \
  acc[mf_][3] = __builtin_amdgcn_mfma_f32_16x16x32_bf16(a_, b3, acc[mf_][3], 0, 0, 0)

#define PH_TAIL                                   \
  __builtin_amdgcn_s_barrier();                   \
  asm volatile("s_waitcnt lgkmcnt(0)" ::: "memory"); \
  __builtin_amdgcn_sched_barrier(0);              \
  __builtin_amdgcn_s_setprio(1)
#define PH_END                                    \
  __builtin_amdgcn_s_setprio(0);                  \
  __builtin_amdgcn_s_barrier();                   \
  __builtin_amdgcn_sched_barrier(0)

  f32x4 acc[8][4] = {};

  SB0(0, 0); SB1(0, 0); SAI0(0, 0); SAI1(0, 0);
  asm volatile("s_waitcnt vmcnt(2)" ::: "memory");
  __builtin_amdgcn_s_barrier();

  for (int t = 0; t < 16; ++t) {
    const int p = t & 1, q = p ^ 1;
    const short* Ah = lds + p * 32768 + mh * 8192;
    const short* Bh = lds + p * 32768 + 16384 + bhsel * 8192;
    bf16x8 b0, b1, b2, b3, a0, a1, a2, a3;
    // ph1
    b0 = LDB(0, swzk0); b1 = LDB(1, swzk0); b2 = LDB(2, swzk0); b3 = LDB(3, swzk0);
    a0 = LDA(0, swzk0); a1 = LDA(1, swzk0); a2 = LDA(2, swzk0); a3 = LDA(3, swzk0);
    if (t < 15) {
      SB0(t + 1, q);
      asm volatile("s_waitcnt vmcnt(2)" ::: "memory");
    } else {
      asm volatile("s_waitcnt vmcnt(0)" ::: "memory");
    }
    PH_TAIL;
    MMROW(0, a0); MMROW(1, a1); MMROW(2, a2); MMROW(3, a3);
    PH_END;
    // ph2
    a0 = LDA(4, swzk0); a1 = LDA(5, swzk0); a2 = LDA(6, swzk0); a3 = LDA(7, swzk0);
    if (t < 15) SB1(t + 1, q);
    PH_TAIL;
    MMROW(4, a0); MMROW(5, a1); MMROW(6, a2); MMROW(7, a3);
    PH_END;
    // ph3
    b0 = LDB(0, swzk1); b1 = LDB(1, swzk1); b2 = LDB(2, swzk1); b3 = LDB(3, swzk1);
    a0 = LDA(0, swzk1); a1 = LDA(1, swzk1); a2 = LDA(2, swzk1); a3 = LDA(3, swzk1);
    if (t < 15) SAI0(t + 1, q);
    PH_TAIL;
    MMROW(0, a0); MMROW(1, a1); MMROW(2, a2); MMROW(3, a3);
    PH_END;
    // ph4
    a0 = LDA(4, swzk1); a1 = LDA(5, swzk1); a2 = LDA(6, swzk1); a3 = LDA(7, swzk1);
    if (t < 15) {
      SAI1(t + 1, q);
      asm volatile("s_waitcnt vmcnt(2)" ::: "memory");
    }
    PH_TAIL;
    MMROW(4, a0); MMROW(5, a1); MMROW(6, a2); MMROW(7, a3);
    PH_END;
  }

  const int rsub = (l >> 4) * 4;
#pragma unroll
  for (int mf = 0; mf < 8; mf++)
#pragma unroll
    for (int j = 0; j < 4; j++) {
      const int row = m0 + mh * 128 + mf * 16 + rsub + j;
      short* Up = U + (size_t)row * HS + bx * 128 + wn4 * 32 + lr;
#pragma unroll
      for (int nfp = 0; nfp < 2; nfp++) {
        const float a = acc[mf][nfp][j];
        const float b = acc[mf][nfp + 2][j];
        Up[nfp * 16] = f2b(a / (1.f + expf(-a)) * b);
      }
    }
#undef SB0
#undef SB1
#undef SAI0
#undef SAI1
#undef LDA
#undef LDB
#undef MMROW
#undef PH_TAIL
#undef PH_END
}

// ========== grouped: 128x256 BK=64, 3-buffer pipeline, COMPACT dispatch ======
// grid (4, 72): blockIdx.y indexes the dense tile table (te, tm); <=71 tiles.
// MODE 1: A=xb gathered perm>>1, GELU -> hexpb[gi].
// MODE 2: A=hexpb slot-dense, gate*scatter -> yb.
template <int MODE>
__global__ __launch_bounds__(512, 1) void moe_grp_8ph(
    const short* __restrict__ A, const short* __restrict__ B, short* __restrict__ Cout,
    const int* __restrict__ perm, const int* __restrict__ offs,
    const float* __restrict__ gates, const int* __restrict__ te,
    const int* __restrict__ tm, const int* __restrict__ ntile) {
  extern __shared__ short lds[];
  const int td = threadIdx.x;
  const int ty = blockIdx.y;
  if (ty >= ntile[0]) return;
  const int bx = blockIdx.x;        // 256-col N tile
  const int e = te[ty];
  const int m0 = tm[ty];
  const int rbeg = offs[e], rend = offs[e + 1];
  const short* Bbase = B + ((size_t)e * 1024 + bx * 256) * 1024;

  const int srow = td >> 3;
  const int colsw8 = ((td & 7) ^ (srow & 7)) * 8;
  const short* apx[2];
  const short* bpx[4];
#pragma unroll
  for (int i = 0; i < 2; i++) {
    const int trow = i * 64 + srow;
    int grow;
    if (MODE == 1) grow = perm[min(rbeg + m0 + trow, rend - 1)] >> 1;
    else grow = min(rbeg + m0 + trow, rend - 1);
    apx[i] = A + (size_t)grow * 1024 + colsw8;
  }
#pragma unroll
  for (int u = 0; u < 4; u++)
    bpx[u] = Bbase + (size_t)(u * 64 + srow) * 1024 + colsw8;

#define SA(i_, t_, b_) gl_lds16(apx[i_] + (t_) * 64, lds + (b_) * 24576 + (i_) * 4096 + td * 8)
#define SB(u_, t_, b_) gl_lds16(bpx[u_] + (t_) * 64, lds + (b_) * 24576 + 8192 + (u_) * 4096 + td * 8)

  const int l = td & 63;
  const int wid = td >> 6;
  const int mh = wid >> 2;          // 0,1: 64-row half of the 128-row tile
  const int wn4 = wid & 3;          // 64-col quarter (and B unit index)
  const int lr = l & 15;
  const int swzk0 = ((0 + (l >> 4) * 16) ^ ((l & 7) << 4)) >> 1;
  const int swzk1 = ((64 + (l >> 4) * 16) ^ ((l & 7) << 4)) >> 1;

#define LDA(mf_, swz_) (*(const bf16x8*)&Ah[(unsigned)(((mf_)*16 + lr) * 64) + (swz_)])
#define LDB(nf_, swz_) (*(const bf16x8*)&Bh[(unsigned)(((nf_)*16 + lr) * 64) + (swz_)])
#define MMROW(mf_, a_)                                                                 \
  acc[mf_][0] = __builtin_amdgcn_mfma_f32_16x16x32_bf16(a_, b0, acc[mf_][0], 0, 0, 0); \
  acc[mf_][1] = __builtin_amdgcn_mfma_f32_16x16x32_bf16(a_, b1, acc[mf_][1], 0, 0, 0); \
  acc[mf_][2] = __builtin_amdgcn_mfma_f32_16x16x32_bf16(a_, b2, acc[mf_][2], 0, 0, 0); \
  acc[mf_][3] = __builtin_amdgcn_mfma_f32_16x16x32_bf16(a_, b3, acc[mf_][3], 0, 0, 0)

#define PH_TAIL                                   \
  __builtin_amdgcn_s_barrier();                   \
  asm volatile("s_waitcnt lgkmcnt(0)" ::: "memory"); \
  __builtin_amdgcn_sched_barrier(0);              \
  __builtin_amdgcn_s_setprio(1)
#define PH_END                                    \
  __builtin_amdgcn_s_setprio(0);                  \
  __builtin_amdgcn_s_barrier();                   \
  __builtin_amdgcn_sched_barrier(0)

  f32x4 acc[4][4] = {};

  // prologue: stage tiles 0 (buf0) and 1 (buf1); ensure tile 0 landed (leave 6)
  SA(0, 0, 0); SA(1, 0, 0); SB(0, 0, 0); SB(1, 0, 0); SB(2, 0, 0); SB(3, 0, 0);
  SA(0, 1, 1); SA(1, 1, 1); SB(0, 1, 1); SB(1, 1, 1); SB(2, 1, 1); SB(3, 1, 1);
  asm volatile("s_waitcnt vmcnt(6)" ::: "memory");
  __builtin_amdgcn_s_barrier();

  int pb = 0;  // buffer of tile t
  int sb = 2;  // buffer of tile t+2 (stage target)
  for (int t = 0; t < 16; ++t) {
    const short* Ah = lds + pb * 24576 + mh * 4096;
    const short* Bh = lds + pb * 24576 + 8192 + wn4 * 4096;
    bf16x8 b0, b1, b2, b3, a0, a1;
    // ph1: k0, mf0-1
    b0 = LDB(0, swzk0); b1 = LDB(1, swzk0); b2 = LDB(2, swzk0); b3 = LDB(3, swzk0);
    a0 = LDA(0, swzk0); a1 = LDA(1, swzk0);
    if (t <= 13) { SB(0, t + 2, sb); SB(1, t + 2, sb); }
    PH_TAIL;
    MMROW(0, a0); MMROW(1, a1);
    PH_END;
    // ph2: k0, mf2-3 (b regs held)
    a0 = LDA(2, swzk0); a1 = LDA(3, swzk0);
    if (t <= 13) { SB(2, t + 2, sb); SB(3, t + 2, sb); }
    PH_TAIL;
    MMROW(2, a0); MMROW(3, a1);
    PH_END;
    // ph3: k1, mf0-1
    b0 = LDB(0, swzk1); b1 = LDB(1, swzk1); b2 = LDB(2, swzk1); b3 = LDB(3, swzk1);
    a0 = LDA(0, swzk1); a1 = LDA(1, swzk1);
    if (t <= 13) { SA(0, t + 2, sb); SA(1, t + 2, sb); }
    PH_TAIL;
    MMROW(0, a0); MMROW(1, a1);
    PH_END;
    // ph4: k1, mf2-3; then the per-tile wait covering tile t+1
    a0 = LDA(2, swzk1); a1 = LDA(3, swzk1);
    PH_TAIL;
    MMROW(2, a0); MMROW(3, a1);
    __builtin_amdgcn_s_setprio(0);
    if (t < 14) {
      asm volatile("s_waitcnt vmcnt(6)" ::: "memory");  // t+1 landed; t+2 in flight
    } else {
      asm volatile("s_waitcnt vmcnt(0)" ::: "memory");  // tail drain
    }
    __builtin_amdgcn_s_barrier();
    __builtin_amdgcn_sched_barrier(0);
    pb = (pb == 2) ? 0 : pb + 1;
    sb = (sb == 2) ? 0 : sb + 1;
  }

  // ---- epilogue ----
  const int rsub = (l >> 4) * 4;
#pragma unroll
  for (int mf = 0; mf < 4; mf++)
#pragma unroll
    for (int j = 0; j < 4; j++) {
      const int gi = rbeg + m0 + mh * 64 + mf * 16 + rsub + j;
      if (gi < rend) {
        if (MODE == 1) {
          short* Cp = Cout + (size_t)gi * HE + bx * 256 + wn4 * 64 + lr;
#pragma unroll
          for (int nf = 0; nf < 4; nf++) {
            const float v = acc[mf][nf][j];
            Cp[nf * 16] = f2b(0.5f * v * (1.0f + erff(v * 0.70710678118654752f)));
          }
        } else {
          const int slot = perm[gi];
          const float g = gates[slot];
          short* Cp = Cout + (size_t)slot * D_MODEL + bx * 256 + wn4 * 64 + lr;
#pragma unroll
          for (int nf = 0; nf < 4; nf++) Cp[nf * 16] = f2b(g * acc[mf][nf][j]);
        }
      }
    }
#undef SA
#undef SB
#undef LDA
#undef LDB
#undef MMROW
#undef PH_TAIL
#undef PH_END
}

// ---------------- G2: shared = u @ w2, fused final combine (2-phase 128²) ----
__global__ __launch_bounds__(256, 2) void gemm_g2(
    const short* __restrict__ A, const short* __restrict__ B,
    const short* __restrict__ yb, float* __restrict__ out) {
  __shared__ __align__(16) short As[4096];
  __shared__ __align__(16) short Bs[4096];
  const int t = threadIdx.x;
  const int tile_n = blockIdx.x * 128;  // over D_MODEL
  const int m0 = blockIdx.y * 128;
  const int r = t >> 2;
  const int c8 = (t & 3) * 8;
  const short* Ap0 = A + (size_t)(m0 + r) * HS + c8;
  const short* Ap1 = A + (size_t)(m0 + 64 + r) * HS + c8;
  const short* Bp0 = B + (size_t)(tile_n + r) * HS + c8;
  const short* Bp1 = B + (size_t)(tile_n + 64 + r) * HS + c8;

  const int lane = t & 63, wv = t >> 6;
  const int wm = (wv >> 1) * 64, wn = (wv & 1) * 64;
  const int lr = lane & 15, lk = (lane >> 4) * 8;

  f32x4 acc[4][4] = {};
  for (int k0 = 0; k0 < HS; k0 += 32) {
    gl_lds16(Ap0 + k0, &As[t * 8]);
    gl_lds16(Ap1 + k0, &As[2048 + t * 8]);
    gl_lds16(Bp0 + k0, &Bs[t * 8]);
    gl_lds16(Bp1 + k0, &Bs[2048 + t * 8]);
    __syncthreads();
    bf16x8 af[4], bfr[4];
#pragma unroll
    for (int m = 0; m < 4; m++) af[m] = *(const bf16x8*)&As[(wm + m * 16 + lr) * 32 + lk];
#pragma unroll
    for (int n = 0; n < 4; n++) bfr[n] = *(const bf16x8*)&Bs[(wn + n * 16 + lr) * 32 + lk];
#pragma unroll
    for (int m = 0; m < 4; m++)
#pragma unroll
      for (int n = 0; n < 4; n++)
        acc[m][n] = __builtin_amdgcn_mfma_f32_16x16x32_bf16(af[m], bfr[n], acc[m][n], 0, 0, 0);
    __syncthreads();
  }

  const int rq = (lane >> 4) * 4;
  const float inv3 = 1.0f / 3.0f;
#pragma unroll
  for (int m = 0; m < 4; m++) {
#pragma unroll
    for (int j = 0; j < 4; j++) {
      const int tok = m0 + wm + m * 16 + rq + j;
      const int colb = tile_n + wn + lr;
      const short* y0p = yb + (size_t)(tok * 2) * D_MODEL + colb;
      const short* y1p = yb + (size_t)(tok * 2 + 1) * D_MODEL + colb;
      float* Op = out + (size_t)tok * D_MODEL + colb;
#pragma unroll
      for (int n = 0; n < 4; n++) {
        Op[n * 16] = (acc[m][n][j] + b2f(y0p[n * 16]) + b2f(y1p[n * 16])) * inv3;
      }
    }
  }
}

// ---------------- launch ----------------
extern "C" void kernel_launch(void* const* d_in, const int* in_sizes, int n_in,
                              void* d_out, int out_size, void* d_ws, size_t ws_size,
                              hipStream_t stream) {
  const float* x = (const float*)d_in[0];
  const float* temb = (const float*)d_in[1];
  const float* rw = (const float*)d_in[2];
  const float* rbias = (const float*)d_in[3];
  const float* w1 = (const float*)d_in[4];
  const float* w3 = (const float*)d_in[5];
  const float* w2 = (const float*)d_in[6];
  const float* W1e = (const float*)d_in[7];
  const float* W2e = (const float*)d_in[8];
  float* out = (float*)d_out;

  const size_t MB = 1ull << 20;
  char* w = (char*)d_ws;
  short* xb    = (short*)(w + 0 * MB);    // 8 MB  [4096][1024]
  short* w13I  = (short*)(w + 8 * MB);    // 8 MB  [4096][1024] interleaved w1/w3
  short* w2T   = (short*)(w + 16 * MB);   // 4 MB  [1024][2048]
  short* W1eT  = (short*)(w + 20 * MB);   // 16 MB [8][1024][1024]
  short* W2eT  = (short*)(w + 36 * MB);   // 16 MB [8][1024][1024]
  short* ubuf  = (short*)(w + 52 * MB);   // 16 MB [4096][2048]
  short* hexpb = (short*)(w + 68 * MB);   // 16 MB [8192][1024]
  short* yb    = (short*)(w + 84 * MB);   // 16 MB [8192][1024] gated bf16
  float* gates = (float*)(w + 100 * MB);  // 32 KB
  int* topk    = (int*)(w + 100 * MB + 32 * 1024);
  int* perm    = (int*)(w + 100 * MB + 64 * 1024);
  int* meta    = (int*)(w + 100 * MB + 96 * 1024);
  int* offs    = meta;           // 9 ints
  int* te      = meta + 16;      // <=71
  int* tm      = meta + 128;     // <=71
  int* ntile   = meta + 256;     // 1

  hipFuncSetAttribute((const void*)&gemm_g1_8ph,
                      hipFuncAttributeMaxDynamicSharedMemorySize, 131072);
  hipFuncSetAttribute((const void*)&moe_grp_8ph<1>,
                      hipFuncAttributeMaxDynamicSharedMemorySize, 147456);
  hipFuncSetAttribute((const void*)&moe_grp_8ph<2>,
                      hipFuncAttributeMaxDynamicSharedMemorySize, 147456);

  // prep
  cvt_x_kernel<<<NTOK * D_MODEL / 4 / 256, 256, 0, stream>>>(x, xb);
  transpose_cvt<1><<<dim3(HS / 64, D_MODEL / 64, 1), 256, 0, stream>>>(w1, w13I, D_MODEL, HS);
  transpose_cvt<2><<<dim3(HS / 64, D_MODEL / 64, 1), 256, 0, stream>>>(w3, w13I, D_MODEL, HS);
  transpose_cvt<0><<<dim3(D_MODEL / 64, HS / 64, 1), 256, 0, stream>>>(w2, w2T, HS, D_MODEL);
  transpose_cvt<0><<<dim3(HE / 64, D_MODEL / 64, NEXP), 256, 0, stream>>>(W1e, W1eT, D_MODEL, HE);
  transpose_cvt<0><<<dim3(D_MODEL / 64, HE / 64, NEXP), 256, 0, stream>>>(W2e, W2eT, HE, D_MODEL);
  router_kernel<<<NTOK / 4, 256, 0, stream>>>(x, temb, rw, rbias, topk, gates);
  group_kernel<<<1, 1024, 0, stream>>>(topk, perm, offs, te, tm, ntile);

  // G1: u = silu(x@w1)*(x@w3)
  gemm_g1_8ph<<<dim3(HS / 128, NTOK / 256, 1), 512, 131072, stream>>>(xb, w13I, ubuf);

  // routed experts: compact tile-table dispatch (<=71 active + <=1 exit per bx)
  moe_grp_8ph<1><<<dim3(HE / 256, 72, 1), 512, 147456, stream>>>(
      xb, W1eT, hexpb, perm, offs, gates, te, tm, ntile);
  moe_grp_8ph<2><<<dim3(D_MODEL / 256, 72, 1), 512, 147456, stream>>>(
      hexpb, W2eT, yb, perm, offs, gates, te, tm, ntile);

  // shared down-proj + final combine
  gemm_g2<<<dim3(D_MODEL / 128, NTOK / 128, 1), 256, 0, stream>>>(ubuf, w2T, yb, out);
}

// Round 9
// 243.839 us; speedup vs baseline: 1.0590x; 1.0590x over previous
//
#include <hip/hip_runtime.h>
#include <hip/hip_bf16.h>
#include <math.h>

#define D_MODEL 1024
#define HS 2048
#define HE 1024
#define NEXP 8
#define NTOK 4096
#define NSLOT 8192

typedef __attribute__((ext_vector_type(4))) float f32x4;
typedef __attribute__((ext_vector_type(8))) short bf16x8;

__device__ __forceinline__ short f2b(float f) {
  __hip_bfloat16 h = __float2bfloat16(f);
  return *reinterpret_cast<short*>(&h);
}
__device__ __forceinline__ float b2f(short s) {
  return __bfloat162float(*reinterpret_cast<__hip_bfloat16*>(&s));
}

__device__ __forceinline__ void gl_lds16(const short* g, short* l) {
  __builtin_amdgcn_global_load_lds(
      (const __attribute__((address_space(1))) void*)g,
      (__attribute__((address_space(3))) void*)l, 16, 0, 0);
}

// ---------------- converts ----------------
__global__ __launch_bounds__(256) void cvt_x_kernel(const float* __restrict__ in,
                                                    short* __restrict__ out) {
  int i = blockIdx.x * 256 + threadIdx.x;  // over NTOK*D/4
  const float4 v = ((const float4*)in)[i];
  short4 o;
  o.x = f2b(v.x); o.y = f2b(v.y); o.z = f2b(v.z); o.w = f2b(v.w);
  ((short4*)out)[i] = o;
}

// shared transpose tile body: in [R][C] f32 -> out bf16 transposed.
// rmap 0: plain [C][R]; rmap 1/2: w13I interleave out_row=(c>>5)*64+(rmap==2?32:0)+(c&31)
__device__ __forceinline__ void tr_tile(const float* __restrict__ in,
                                        short* __restrict__ out, int R, int C,
                                        int bx, int by, int bz, int rmap,
                                        float (*tile)[69], int t) {
  const int c0 = bx * 64;
  const int r0 = by * 64;
  const size_t bo = (size_t)bz * R * C;
  const int lr = t >> 4;
  const int lc4 = (t & 15) * 4;
#pragma unroll
  for (int i = 0; i < 4; i++) {
    const float4 v = *(const float4*)&in[bo + (size_t)(r0 + lr + i * 16) * C + c0 + lc4];
    tile[lc4 + 0][lr + i * 16] = v.x;
    tile[lc4 + 1][lr + i * 16] = v.y;
    tile[lc4 + 2][lr + i * 16] = v.z;
    tile[lc4 + 3][lr + i * 16] = v.w;
  }
  __syncthreads();
#pragma unroll
  for (int i = 0; i < 4; i++) {
    const int oc = (t >> 4) + i * 16;
    const int or4 = (t & 15) * 4;
    short4 o;
    o.x = f2b(tile[oc][or4 + 0]);
    o.y = f2b(tile[oc][or4 + 1]);
    o.z = f2b(tile[oc][or4 + 2]);
    o.w = f2b(tile[oc][or4 + 3]);
    const int c = c0 + oc;
    size_t orow;
    if (rmap == 0) orow = bo + (size_t)c * R;
    else orow = (size_t)((c >> 5) * 64 + (rmap == 2 ? 32 : 0) + (c & 31)) * R;
    *(short4*)&out[orow + r0 + or4] = o;
  }
}

// w1 (z=0, rmap1) and w3 (z=1, rmap2) -> w13I. grid (32, 16, 2)
__global__ __launch_bounds__(256) void tr_w13(const float* __restrict__ w1,
                                              const float* __restrict__ w3,
                                              short* __restrict__ w13I) {
  __shared__ float tile[64][69];
  const int z = blockIdx.z;
  tr_tile(z ? w3 : w1, w13I, D_MODEL, HS, blockIdx.x, blockIdx.y, 0, z ? 2 : 1,
          tile, threadIdx.x);
}

// w2 [HS][D] -> w2T [D][HS]. grid (16, 32)
__global__ __launch_bounds__(256) void tr_w2(const float* __restrict__ w2,
                                             short* __restrict__ w2T) {
  __shared__ float tile[64][69];
  tr_tile(w2, w2T, HS, D_MODEL, blockIdx.x, blockIdx.y, 0, 0, tile, threadIdx.x);
}

// W1e (z<8) and W2e (z>=8) -> transposed. grid (16, 16, 16)
__global__ __launch_bounds__(256) void tr_exp(const float* __restrict__ W1e,
                                              const float* __restrict__ W2e,
                                              short* __restrict__ W1eT,
                                              short* __restrict__ W2eT) {
  __shared__ float tile[64][69];
  const int z = blockIdx.z;
  if (z < 8)
    tr_tile(W1e, W1eT, D_MODEL, HE, blockIdx.x, blockIdx.y, z, 0, tile, threadIdx.x);
  else
    tr_tile(W2e, W2eT, HE, D_MODEL, blockIdx.x, blockIdx.y, z - 8, 0, tile, threadIdx.x);
}

// ---------------- router (wave per token, float4) ----------------
__global__ __launch_bounds__(256) void router_kernel(
    const float* __restrict__ x, const float* __restrict__ temb,
    const float* __restrict__ rw, const float* __restrict__ rbias,
    int* __restrict__ topk, float* __restrict__ gates) {
  const int t = (blockIdx.x * 256 + threadIdx.x) >> 6;
  const int lane = threadIdx.x & 63;
  const float* xr = x + (size_t)t * D_MODEL;
  const float* tr = temb + (size_t)(t >> 10) * D_MODEL;  // T=1024
  float acc[NEXP] = {};
#pragma unroll
  for (int i = 0; i < 4; i++) {
    const int j = i * 256 + lane * 4;
    const float4 xv = *(const float4*)&xr[j];
    const float4 tv = *(const float4*)&tr[j];
    const float* wx = rw + (size_t)j * NEXP;
    const float* wt = rw + (size_t)(D_MODEL + j) * NEXP;
    const float xa[4] = {xv.x, xv.y, xv.z, xv.w};
    const float ta[4] = {tv.x, tv.y, tv.z, tv.w};
#pragma unroll
    for (int u = 0; u < 4; u++)
#pragma unroll
      for (int e = 0; e < NEXP; e++)
        acc[e] += xa[u] * wx[u * NEXP + e] + ta[u] * wt[u * NEXP + e];
  }
#pragma unroll
  for (int off = 32; off; off >>= 1)
#pragma unroll
    for (int e = 0; e < NEXP; e++) acc[e] += __shfl_xor(acc[e], off);
  if (lane == 0) {
    float s[NEXP], sel[NEXP];
#pragma unroll
    for (int e = 0; e < NEXP; e++) {
      s[e] = 1.f / (1.f + expf(-acc[e]));
      sel[e] = s[e] + rbias[e];
    }
    int i0 = 0;
#pragma unroll
    for (int e = 1; e < NEXP; e++) if (sel[e] > sel[i0]) i0 = e;
    int i1 = (i0 == 0) ? 1 : 0;
#pragma unroll
    for (int e = 0; e < NEXP; e++) if (e != i0 && sel[e] > sel[i1]) i1 = e;
    float s0 = s[i0], s1 = s[i1], den = s0 + s1;
    float g0, g1;
    if (den > 1e-9f) { g0 = s0 / (den + 1e-9f); g1 = s1 / (den + 1e-9f); }
    else { g0 = 0.5f; g1 = 0.5f; }
    topk[t * 2] = i0; topk[t * 2 + 1] = i1;
    gates[t * 2] = g0; gates[t * 2 + 1] = g1;
  }
}

// ------- grouping: hist + scan + fill + BM=256 tile table in one block ------
__global__ __launch_bounds__(1024) void group_kernel(const int* __restrict__ topk,
                                                     int* __restrict__ perm,
                                                     int* __restrict__ offs,
                                                     int* __restrict__ te,
                                                     int* __restrict__ tm,
                                                     int* __restrict__ ntile) {
  __shared__ int cnt[NEXP], cur[NEXP];
  const int t = threadIdx.x;
  if (t < NEXP) cnt[t] = 0;
  __syncthreads();
  int mye[8];
#pragma unroll
  for (int i = 0; i < 8; i++) {
    mye[i] = topk[i * 1024 + t];
    atomicAdd(&cnt[mye[i]], 1);
  }
  __syncthreads();
  if (t == 0) {
    int a = 0;
    for (int e = 0; e < NEXP; e++) { offs[e] = a; cur[e] = a; a += cnt[e]; }
    offs[NEXP] = a;
    int nt = 0;
    for (int e = 0; e < NEXP; e++)
      for (int m0 = 0; m0 < cnt[e]; m0 += 256) { te[nt] = e; tm[nt] = m0; nt++; }
    ntile[0] = nt;  // <= 40
  }
  __syncthreads();
#pragma unroll
  for (int i = 0; i < 8; i++) {
    int pos = atomicAdd(&cur[mye[i]], 1);
    perm[pos] = i * 1024 + t;
  }
}

// ============ unified 256x256 BK=64 8-wave per-phase-barrier GEMM ============
// MODE 0 (G1): A=xb dense, B=w13I, silu*mul -> ubuf. grid 256 (1D, XCD rect).
// MODE 1: A=xb gathered perm>>1, B=W1eT[e], GELU -> hexpb[gi]. grid 160 (1D).
// MODE 2: A=hexpb slot-dense, B=W2eT[e], gate*scatter -> yb. grid 160 (1D).
// Staging FRONT-LOADED: ph1 issues both B units (U1,U2) of t+1, ph2 both A
// units (U3,U4). Waits: ph1 vmcnt(4) [targets U4(t), 3 phases old], ph4
// vmcnt(2) [targets U1-U3(t+1), >=2 phases old]. No wait touches a load
// issued <2 phases ago (R8 theory: 1-phase-old waits stalled every ph1/ph4).
template <int MODE>
__global__ __launch_bounds__(512, 1) void moe_gemm_8ph(
    const short* __restrict__ A, const short* __restrict__ B, short* __restrict__ Cout,
    const int* __restrict__ perm, const int* __restrict__ offs,
    const float* __restrict__ gates, const int* __restrict__ te,
    const int* __restrict__ tm, const int* __restrict__ ntile) {
  extern __shared__ short lds[];
  const int td = threadIdx.x;
  int bx, m0, rbeg = 0, rend = 0;
  const short* Bbase;
  if (MODE == 0) {
    const int id = blockIdx.x, xcd = id & 7, slot = id >> 3;
    bx = (xcd & 3) * 4 + (slot & 3);            // 0..15
    m0 = ((xcd >> 2) * 8 + (slot >> 2)) * 256;  // 16 panels
    Bbase = B + (size_t)bx * 256 * 1024;
  } else {
    const int id = blockIdx.x;                  // grid 160 = 8*20
    const int work = (id & 7) * 20 + (id >> 3); // XCD chunk of 20 works
    const int ty = work >> 2;
    if (ty >= ntile[0]) return;
    bx = work & 3;
    const int e = te[ty];
    m0 = tm[ty];
    rbeg = offs[e]; rend = offs[e + 1];
    Bbase = B + ((size_t)e * 1024 + bx * 256) * 1024;
  }

  // staging source pointers (global col pre-swizzled, rule 21)
  const int srow = td >> 3;
  const int colsw8 = ((td & 7) ^ (srow & 7)) * 8;
  const short* ap[2][2];
  const short* bp[2][2];
#pragma unroll
  for (int h = 0; h < 2; h++)
#pragma unroll
    for (int i = 0; i < 2; i++) {
      const int trow = h * 128 + i * 64 + srow;
      int grow;
      if (MODE == 0) grow = m0 + trow;
      else if (MODE == 1) grow = perm[min(rbeg + m0 + trow, rend - 1)] >> 1;
      else grow = min(rbeg + m0 + trow, rend - 1);
      ap[h][i] = A + (size_t)grow * 1024 + colsw8;
      bp[h][i] = Bbase + (size_t)trow * 1024 + colsw8;
    }

// U1: B rows 0..127 | U2: B rows 128..255 | U3: A i0-rows | U4: A i1-rows
#define SU1(t_, b_)                                                        \
  do {                                                                     \
    gl_lds16(bp[0][0] + (t_) * 64, lds + (b_) * 32768 + 16384 + td * 8);   \
    gl_lds16(bp[0][1] + (t_) * 64, lds + (b_) * 32768 + 16384 + 4096 + td * 8); \
  } while (0)
#define SU2(t_, b_)                                                        \
  do {                                                                     \
    gl_lds16(bp[1][0] + (t_) * 64, lds + (b_) * 32768 + 16384 + 8192 + td * 8); \
    gl_lds16(bp[1][1] + (t_) * 64, lds + (b_) * 32768 + 16384 + 8192 + 4096 + td * 8); \
  } while (0)
#define SU3(t_, b_)                                                        \
  do {                                                                     \
    gl_lds16(ap[0][0] + (t_) * 64, lds + (b_) * 32768 + td * 8);           \
    gl_lds16(ap[1][0] + (t_) * 64, lds + (b_) * 32768 + 8192 + td * 8);    \
  } while (0)
#define SU4(t_, b_)                                                        \
  do {                                                                     \
    gl_lds16(ap[0][1] + (t_) * 64, lds + (b_) * 32768 + 4096 + td * 8);    \
    gl_lds16(ap[1][1] + (t_) * 64, lds + (b_) * 32768 + 8192 + 4096 + td * 8); \
  } while (0)

  const int l = td & 63;
  const int wid = td >> 6;
  const int mh = wid >> 2;
  const int wn4 = wid & 3;
  const int lr = l & 15;
  const int bhsel = wn4 >> 1;
  const int bnr = (wn4 & 1) * 64;
  const int swzk0 = ((0 + (l >> 4) * 16) ^ ((l & 7) << 4)) >> 1;
  const int swzk1 = ((64 + (l >> 4) * 16) ^ ((l & 7) << 4)) >> 1;

#define LDA(mf_, swz_) (*(const bf16x8*)&Ah[(unsigned)(((mf_)*16 + lr) * 64) + (swz_)])
#define LDB(nf_, swz_) (*(const bf16x8*)&Bh[(unsigned)((bnr + (nf_)*16 + lr) * 64) + (swz_)])
#define MMROW(mf_, a_)                                                                 \
  acc[mf_][0] = __builtin_amdgcn_mfma_f32_16x16x32_bf16(a_, b0, acc[mf_][0], 0, 0, 0); \
  acc[mf_][1] = __builtin_amdgcn_mfma_f32_16x16x32_bf16(a_, b1, acc[mf_][1], 0, 0, 0); \
  acc[mf_][2] = __builtin_amdgcn_mfma_f32_16x16x32_bf16(a_, b2, acc[mf_][2], 0, 0, 0); \
  acc[mf_][3] = __builtin_amdgcn_mfma_f32_16x16x32_bf16(a_, b3, acc[mf_][3], 0, 0, 0)

#define PH_TAIL                                   \
  __builtin_amdgcn_s_barrier();                   \
  asm volatile("s_waitcnt lgkmcnt(0)" ::: "memory"); \
  __builtin_amdgcn_sched_barrier(0);              \
  __builtin_amdgcn_s_setprio(1)
#define PH_END                                    \
  __builtin_amdgcn_s_setprio(0);                  \
  __builtin_amdgcn_s_barrier();                   \
  __builtin_amdgcn_sched_barrier(0)

  f32x4 acc[8][4] = {};

  // prologue: tile 0 -> buf 0; wait U1-U3 landed (U4(0) stays in flight)
  SU1(0, 0); SU2(0, 0); SU3(0, 0); SU4(0, 0);
  asm volatile("s_waitcnt vmcnt(2)" ::: "memory");
  __builtin_amdgcn_s_barrier();

  for (int t = 0; t < 16; ++t) {
    const int p = t & 1, q = p ^ 1;
    const short* Ah = lds + p * 32768 + mh * 8192;
    const short* Bh = lds + p * 32768 + 16384 + bhsel * 8192;
    bf16x8 b0, b1, b2, b3, a0, a1, a2, a3;
    // ph1: k0 mf0-3 | issue U1,U2(t+1) | vmcnt(4) -> U4(t) (3 phases old)
    b0 = LDB(0, swzk0); b1 = LDB(1, swzk0); b2 = LDB(2, swzk0); b3 = LDB(3, swzk0);
    a0 = LDA(0, swzk0); a1 = LDA(1, swzk0); a2 = LDA(2, swzk0); a3 = LDA(3, swzk0);
    if (t < 15) {
      SU1(t + 1, q); SU2(t + 1, q);
      asm volatile("s_waitcnt vmcnt(4)" ::: "memory");
    } else {
      asm volatile("s_waitcnt vmcnt(0)" ::: "memory");
    }
    PH_TAIL;
    MMROW(0, a0); MMROW(1, a1); MMROW(2, a2); MMROW(3, a3);
    PH_END;
    // ph2: k0 mf4-7 (needs U4(t), guaranteed) | issue U3,U4(t+1)
    a0 = LDA(4, swzk0); a1 = LDA(5, swzk0); a2 = LDA(6, swzk0); a3 = LDA(7, swzk0);
    if (t < 15) { SU3(t + 1, q); SU4(t + 1, q); }
    PH_TAIL;
    MMROW(4, a0); MMROW(5, a1); MMROW(6, a2); MMROW(7, a3);
    PH_END;
    // ph3: k1 mf0-3 (no staging)
    b0 = LDB(0, swzk1); b1 = LDB(1, swzk1); b2 = LDB(2, swzk1); b3 = LDB(3, swzk1);
    a0 = LDA(0, swzk1); a1 = LDA(1, swzk1); a2 = LDA(2, swzk1); a3 = LDA(3, swzk1);
    PH_TAIL;
    MMROW(0, a0); MMROW(1, a1); MMROW(2, a2); MMROW(3, a3);
    PH_END;
    // ph4: k1 mf4-7 | vmcnt(2) -> U1-U3(t+1) (>=2 phases old), leaves U4(t+1)
    a0 = LDA(4, swzk1); a1 = LDA(5, swzk1); a2 = LDA(6, swzk1); a3 = LDA(7, swzk1);
    if (t < 15) asm volatile("s_waitcnt vmcnt(2)" ::: "memory");
    PH_TAIL;
    MMROW(4, a0); MMROW(5, a1); MMROW(6, a2); MMROW(7, a3);
    PH_END;
  }

  // ---- epilogue ----
  const int rsub = (l >> 4) * 4;
  if (MODE == 0) {
#pragma unroll
    for (int mf = 0; mf < 8; mf++)
#pragma unroll
      for (int j = 0; j < 4; j++) {
        const int row = m0 + mh * 128 + mf * 16 + rsub + j;
        short* Up = Cout + (size_t)row * HS + bx * 128 + wn4 * 32 + lr;
#pragma unroll
        for (int nfp = 0; nfp < 2; nfp++) {
          const float a = acc[mf][nfp][j];
          const float b = acc[mf][nfp + 2][j];
          Up[nfp * 16] = f2b(a / (1.f + expf(-a)) * b);
        }
      }
  } else if (MODE == 1) {
#pragma unroll
    for (int mf = 0; mf < 8; mf++)
#pragma unroll
      for (int j = 0; j < 4; j++) {
        const int gi = rbeg + m0 + mh * 128 + mf * 16 + rsub + j;
        if (gi < rend) {
          short* Cp = Cout + (size_t)gi * HE + bx * 256 + wn4 * 64 + lr;
#pragma unroll
          for (int nf = 0; nf < 4; nf++) {
            const float v = acc[mf][nf][j];
            Cp[nf * 16] = f2b(0.5f * v * (1.0f + erff(v * 0.70710678118654752f)));
          }
        }
      }
  } else {
#pragma unroll
    for (int mf = 0; mf < 8; mf++)
#pragma unroll
      for (int j = 0; j < 4; j++) {
        const int gi = rbeg + m0 + mh * 128 + mf * 16 + rsub + j;
        if (gi < rend) {
          const int slot = perm[gi];
          const float g = gates[slot];
          short* Cp = Cout + (size_t)slot * D_MODEL + bx * 256 + wn4 * 64 + lr;
#pragma unroll
          for (int nf = 0; nf < 4; nf++) Cp[nf * 16] = f2b(g * acc[mf][nf][j]);
        }
      }
  }
#undef SU1
#undef SU2
#undef SU3
#undef SU4
#undef LDA
#undef LDB
#undef MMROW
#undef PH_TAIL
#undef PH_END
}

// ---------------- G2: shared = u @ w2, fused final combine (2-phase 128²) ----
// 1D grid 256, XCD rectangle swizzle (8bx x 4my per XCD).
__global__ __launch_bounds__(256, 2) void gemm_g2(
    const short* __restrict__ A, const short* __restrict__ B,
    const short* __restrict__ yb, float* __restrict__ out) {
  __shared__ __align__(16) short As[4096];
  __shared__ __align__(16) short Bs[4096];
  const int t = threadIdx.x;
  const int id = blockIdx.x, xcd = id & 7, slot = id >> 3;
  const int tile_n = (slot & 7) * 128;              // 8 bx panels
  const int m0 = (xcd * 4 + (slot >> 3)) * 128;     // 32 my panels
  const int r = t >> 2;
  const int c8 = (t & 3) * 8;
  const short* Ap0 = A + (size_t)(m0 + r) * HS + c8;
  const short* Ap1 = A + (size_t)(m0 + 64 + r) * HS + c8;
  const short* Bp0 = B + (size_t)(tile_n + r) * HS + c8;
  const short* Bp1 = B + (size_t)(tile_n + 64 + r) * HS + c8;

  const int lane = t & 63, wv = t >> 6;
  const int wm = (wv >> 1) * 64, wn = (wv & 1) * 64;
  const int lr = lane & 15, lk = (lane >> 4) * 8;

  f32x4 acc[4][4] = {};
  for (int k0 = 0; k0 < HS; k0 += 32) {
    gl_lds16(Ap0 + k0, &As[t * 8]);
    gl_lds16(Ap1 + k0, &As[2048 + t * 8]);
    gl_lds16(Bp0 + k0, &Bs[t * 8]);
    gl_lds16(Bp1 + k0, &Bs[2048 + t * 8]);
    __syncthreads();
    bf16x8 af[4], bfr[4];
#pragma unroll
    for (int m = 0; m < 4; m++) af[m] = *(const bf16x8*)&As[(wm + m * 16 + lr) * 32 + lk];
#pragma unroll
    for (int n = 0; n < 4; n++) bfr[n] = *(const bf16x8*)&Bs[(wn + n * 16 + lr) * 32 + lk];
#pragma unroll
    for (int m = 0; m < 4; m++)
#pragma unroll
      for (int n = 0; n < 4; n++)
        acc[m][n] = __builtin_amdgcn_mfma_f32_16x16x32_bf16(af[m], bfr[n], acc[m][n], 0, 0, 0);
    __syncthreads();
  }

  const int rq = (lane >> 4) * 4;
  const float inv3 = 1.0f / 3.0f;
#pragma unroll
  for (int m = 0; m < 4; m++) {
#pragma unroll
    for (int j = 0; j < 4; j++) {
      const int tok = m0 + wm + m * 16 + rq + j;
      const int colb = tile_n + wn + lr;
      const short* y0p = yb + (size_t)(tok * 2) * D_MODEL + colb;
      const short* y1p = yb + (size_t)(tok * 2 + 1) * D_MODEL + colb;
      float* Op = out + (size_t)tok * D_MODEL + colb;
#pragma unroll
      for (int n = 0; n < 4; n++) {
        Op[n * 16] = (acc[m][n][j] + b2f(y0p[n * 16]) + b2f(y1p[n * 16])) * inv3;
      }
    }
  }
}

// ---------------- launch ----------------
extern "C" void kernel_launch(void* const* d_in, const int* in_sizes, int n_in,
                              void* d_out, int out_size, void* d_ws, size_t ws_size,
                              hipStream_t stream) {
  const float* x = (const float*)d_in[0];
  const float* temb = (const float*)d_in[1];
  const float* rw = (const float*)d_in[2];
  const float* rbias = (const float*)d_in[3];
  const float* w1 = (const float*)d_in[4];
  const float* w3 = (const float*)d_in[5];
  const float* w2 = (const float*)d_in[6];
  const float* W1e = (const float*)d_in[7];
  const float* W2e = (const float*)d_in[8];
  float* out = (float*)d_out;

  const size_t MB = 1ull << 20;
  char* w = (char*)d_ws;
  short* xb    = (short*)(w + 0 * MB);    // 8 MB  [4096][1024]
  short* w13I  = (short*)(w + 8 * MB);    // 8 MB  [4096][1024] interleaved w1/w3
  short* w2T   = (short*)(w + 16 * MB);   // 4 MB  [1024][2048]
  short* W1eT  = (short*)(w + 20 * MB);   // 16 MB [8][1024][1024]
  short* W2eT  = (short*)(w + 36 * MB);   // 16 MB [8][1024][1024]
  short* ubuf  = (short*)(w + 52 * MB);   // 16 MB [4096][2048]
  short* hexpb = (short*)(w + 68 * MB);   // 16 MB [8192][1024]
  short* yb    = (short*)(w + 84 * MB);   // 16 MB [8192][1024] gated bf16
  float* gates = (float*)(w + 100 * MB);  // 32 KB
  int* topk    = (int*)(w + 100 * MB + 32 * 1024);
  int* perm    = (int*)(w + 100 * MB + 64 * 1024);
  int* meta    = (int*)(w + 100 * MB + 96 * 1024);
  int* offs    = meta;           // 9 ints
  int* te      = meta + 16;      // <=40
  int* tm      = meta + 128;     // <=40
  int* ntile   = meta + 256;     // 1

  hipFuncSetAttribute((const void*)&moe_gemm_8ph<0>,
                      hipFuncAttributeMaxDynamicSharedMemorySize, 131072);
  hipFuncSetAttribute((const void*)&moe_gemm_8ph<1>,
                      hipFuncAttributeMaxDynamicSharedMemorySize, 131072);
  hipFuncSetAttribute((const void*)&moe_gemm_8ph<2>,
                      hipFuncAttributeMaxDynamicSharedMemorySize, 131072);

  // prep
  cvt_x_kernel<<<NTOK * D_MODEL / 4 / 256, 256, 0, stream>>>(x, xb);
  tr_w13<<<dim3(HS / 64, D_MODEL / 64, 2), 256, 0, stream>>>(w1, w3, w13I);
  tr_w2<<<dim3(D_MODEL / 64, HS / 64, 1), 256, 0, stream>>>(w2, w2T);
  tr_exp<<<dim3(16, 16, 16), 256, 0, stream>>>(W1e, W2e, W1eT, W2eT);
  router_kernel<<<NTOK / 4, 256, 0, stream>>>(x, temb, rw, rbias, topk, gates);
  group_kernel<<<1, 1024, 0, stream>>>(topk, perm, offs, te, tm, ntile);

  // G1: u = silu(x@w1)*(x@w3)  (256 blocks, XCD rectangles)
  moe_gemm_8ph<0><<<256, 512, 131072, stream>>>(xb, w13I, ubuf, nullptr, nullptr,
                                                nullptr, nullptr, nullptr, nullptr);

  // routed experts: BM=256 compact, <=160 blocks -> single dispatch wave
  moe_gemm_8ph<1><<<160, 512, 131072, stream>>>(xb, W1eT, hexpb, perm, offs,
                                                gates, te, tm, ntile);
  moe_gemm_8ph<2><<<160, 512, 131072, stream>>>(hexpb, W2eT, yb, perm, offs,
                                                gates, te, tm, ntile);

  // shared down-proj + final combine
  gemm_g2<<<256, 256, 0, stream>>>(ubuf, w2T, yb, out);
}

// Round 10
// 236.328 us; speedup vs baseline: 1.0926x; 1.0318x over previous
//
#include <hip/hip_runtime.h>
#include <hip/hip_bf16.h>
#include <math.h>

#define D_MODEL 1024
#define HS 2048
#define HE 1024
#define NEXP 8
#define NTOK 4096
#define NSLOT 8192

typedef __attribute__((ext_vector_type(4))) float f32x4;
typedef __attribute__((ext_vector_type(8))) short bf16x8;

__device__ __forceinline__ short f2b(float f) {
  __hip_bfloat16 h = __float2bfloat16(f);
  return *reinterpret_cast<short*>(&h);
}
__device__ __forceinline__ float b2f(short s) {
  return __bfloat162float(*reinterpret_cast<__hip_bfloat16*>(&s));
}

__device__ __forceinline__ void gl_lds16(const short* g, short* l) {
  __builtin_amdgcn_global_load_lds(
      (const __attribute__((address_space(1))) void*)g,
      (__attribute__((address_space(3))) void*)l, 16, 0, 0);
}

// shared transpose tile body: in [R][C] f32 -> out bf16 transposed.
// rmap 0: plain [C][R]; rmap 1/2: w13I interleave out_row=(c>>5)*64+(rmap==2?32:0)+(c&31)
__device__ __forceinline__ void tr_tile(const float* __restrict__ in,
                                        short* __restrict__ out, int R, int C,
                                        int bx, int by, int bz, int rmap,
                                        float (*tile)[69], int t) {
  const int c0 = bx * 64;
  const int r0 = by * 64;
  const size_t bo = (size_t)bz * R * C;
  const int lr = t >> 4;
  const int lc4 = (t & 15) * 4;
#pragma unroll
  for (int i = 0; i < 4; i++) {
    const float4 v = *(const float4*)&in[bo + (size_t)(r0 + lr + i * 16) * C + c0 + lc4];
    tile[lc4 + 0][lr + i * 16] = v.x;
    tile[lc4 + 1][lr + i * 16] = v.y;
    tile[lc4 + 2][lr + i * 16] = v.z;
    tile[lc4 + 3][lr + i * 16] = v.w;
  }
  __syncthreads();
#pragma unroll
  for (int i = 0; i < 4; i++) {
    const int oc = (t >> 4) + i * 16;
    const int or4 = (t & 15) * 4;
    short4 o;
    o.x = f2b(tile[oc][or4 + 0]);
    o.y = f2b(tile[oc][or4 + 1]);
    o.z = f2b(tile[oc][or4 + 2]);
    o.w = f2b(tile[oc][or4 + 3]);
    const int c = c0 + oc;
    size_t orow;
    if (rmap == 0) orow = bo + (size_t)c * R;
    else orow = (size_t)((c >> 5) * 64 + (rmap == 2 ? 32 : 0) + (c & 31)) * R;
    *(short4*)&out[orow + r0 + or4] = o;
  }
}

// w1 (z=0, rmap1) and w3 (z=1, rmap2) -> w13I. grid (32, 16, 2)
__global__ __launch_bounds__(256) void tr_w13(const float* __restrict__ w1,
                                              const float* __restrict__ w3,
                                              short* __restrict__ w13I) {
  __shared__ float tile[64][69];
  const int z = blockIdx.z;
  tr_tile(z ? w3 : w1, w13I, D_MODEL, HS, blockIdx.x, blockIdx.y, 0, z ? 2 : 1,
          tile, threadIdx.x);
}

// w2 [HS][D] -> w2T [D][HS]. grid (16, 32)
__global__ __launch_bounds__(256) void tr_w2(const float* __restrict__ w2,
                                             short* __restrict__ w2T) {
  __shared__ float tile[64][69];
  tr_tile(w2, w2T, HS, D_MODEL, blockIdx.x, blockIdx.y, 0, 0, tile, threadIdx.x);
}

// W1e (z<8) and W2e (z>=8) -> transposed. grid (16, 16, 16)
__global__ __launch_bounds__(256) void tr_exp(const float* __restrict__ W1e,
                                              const float* __restrict__ W2e,
                                              short* __restrict__ W1eT,
                                              short* __restrict__ W2eT) {
  __shared__ float tile[64][69];
  const int z = blockIdx.z;
  if (z < 8)
    tr_tile(W1e, W1eT, D_MODEL, HE, blockIdx.x, blockIdx.y, z, 0, tile, threadIdx.x);
  else
    tr_tile(W2e, W2eT, HE, D_MODEL, blockIdx.x, blockIdx.y, z - 8, 0, tile, threadIdx.x);
}

// ------- router + x->bf16 convert fused (x is read once for both) -------
__global__ __launch_bounds__(256) void router_kernel(
    const float* __restrict__ x, const float* __restrict__ temb,
    const float* __restrict__ rw, const float* __restrict__ rbias,
    short* __restrict__ xb, int* __restrict__ topk, float* __restrict__ gates) {
  const int t = (blockIdx.x * 256 + threadIdx.x) >> 6;
  const int lane = threadIdx.x & 63;
  const float* xr = x + (size_t)t * D_MODEL;
  const float* tr = temb + (size_t)(t >> 10) * D_MODEL;  // T=1024
  float acc[NEXP] = {};
#pragma unroll
  for (int i = 0; i < 4; i++) {
    const int j = i * 256 + lane * 4;
    const float4 xv = *(const float4*)&xr[j];
    const float4 tv = *(const float4*)&tr[j];
    short4 o;
    o.x = f2b(xv.x); o.y = f2b(xv.y); o.z = f2b(xv.z); o.w = f2b(xv.w);
    *(short4*)&xb[(size_t)t * D_MODEL + j] = o;
    const float* wx = rw + (size_t)j * NEXP;
    const float* wt = rw + (size_t)(D_MODEL + j) * NEXP;
    const float xa[4] = {xv.x, xv.y, xv.z, xv.w};
    const float ta[4] = {tv.x, tv.y, tv.z, tv.w};
#pragma unroll
    for (int u = 0; u < 4; u++)
#pragma unroll
      for (int e = 0; e < NEXP; e++)
        acc[e] += xa[u] * wx[u * NEXP + e] + ta[u] * wt[u * NEXP + e];
  }
#pragma unroll
  for (int off = 32; off; off >>= 1)
#pragma unroll
    for (int e = 0; e < NEXP; e++) acc[e] += __shfl_xor(acc[e], off);
  if (lane == 0) {
    float s[NEXP], sel[NEXP];
#pragma unroll
    for (int e = 0; e < NEXP; e++) {
      s[e] = 1.f / (1.f + expf(-acc[e]));
      sel[e] = s[e] + rbias[e];
    }
    int i0 = 0;
#pragma unroll
    for (int e = 1; e < NEXP; e++) if (sel[e] > sel[i0]) i0 = e;
    int i1 = (i0 == 0) ? 1 : 0;
#pragma unroll
    for (int e = 0; e < NEXP; e++) if (e != i0 && sel[e] > sel[i1]) i1 = e;
    float s0 = s[i0], s1 = s[i1], den = s0 + s1;
    float g0, g1;
    if (den > 1e-9f) { g0 = s0 / (den + 1e-9f); g1 = s1 / (den + 1e-9f); }
    else { g0 = 0.5f; g1 = 0.5f; }
    topk[t * 2] = i0; topk[t * 2 + 1] = i1;
    gates[t * 2] = g0; gates[t * 2 + 1] = g1;
  }
}

// ------- grouping: hist + scan + fill + BM=256 tile table in one block ------
__global__ __launch_bounds__(1024) void group_kernel(const int* __restrict__ topk,
                                                     int* __restrict__ perm,
                                                     int* __restrict__ offs,
                                                     int* __restrict__ te,
                                                     int* __restrict__ tm,
                                                     int* __restrict__ ntile) {
  __shared__ int cnt[NEXP], cur[NEXP];
  const int t = threadIdx.x;
  if (t < NEXP) cnt[t] = 0;
  __syncthreads();
  int mye[8];
#pragma unroll
  for (int i = 0; i < 8; i++) {
    mye[i] = topk[i * 1024 + t];
    atomicAdd(&cnt[mye[i]], 1);
  }
  __syncthreads();
  if (t == 0) {
    int a = 0;
    for (int e = 0; e < NEXP; e++) { offs[e] = a; cur[e] = a; a += cnt[e]; }
    offs[NEXP] = a;
    int nt = 0;
    for (int e = 0; e < NEXP; e++)
      for (int m0 = 0; m0 < cnt[e]; m0 += 256) { te[nt] = e; tm[nt] = m0; nt++; }
    ntile[0] = nt;  // <= 40
  }
  __syncthreads();
#pragma unroll
  for (int i = 0; i < 8; i++) {
    int pos = atomicAdd(&cur[mye[i]], 1);
    perm[pos] = i * 1024 + t;
  }
}

// ============ unified 256x256 BK=64 8-wave per-phase-barrier GEMM ============
// MODE 0 (G1): A=xb dense, B=w13I, silu*mul -> ubuf. grid 256 (1D, XCD rect).
// MODE 1: A=xb gathered perm>>1, B=W1eT[e], GELU -> hexpb[gi]. grid 160 (1D).
// MODE 2: A=hexpb slot-dense, B=W2eT[e], gate*scatter -> yb. grid 160 (1D).
// R10: phases are now EXACTLY the m201 template: {ds_reads; stage; [vmcnt];
// barrier; setprio(1); MFMA; setprio(0); barrier}. The R9 asm-lgkmcnt(0) +
// sched_barrier(0) walls are REMOVED — compiler emits fine-grained lgkmcnt
// between ds_read and MFMA (m97), letting early MFMAs overlap late reads.
// vmcnt asm ("memory") still fences LDS reads against staging guarantees.
template <int MODE>
__global__ __launch_bounds__(512, 1) void moe_gemm_8ph(
    const short* __restrict__ A, const short* __restrict__ B, short* __restrict__ Cout,
    const int* __restrict__ perm, const int* __restrict__ offs,
    const float* __restrict__ gates, const int* __restrict__ te,
    const int* __restrict__ tm, const int* __restrict__ ntile) {
  extern __shared__ short lds[];
  const int td = threadIdx.x;
  int bx, m0, rbeg = 0, rend = 0;
  const short* Bbase;
  if (MODE == 0) {
    const int id = blockIdx.x, xcd = id & 7, slot = id >> 3;
    bx = (xcd & 3) * 4 + (slot & 3);            // 0..15
    m0 = ((xcd >> 2) * 8 + (slot >> 2)) * 256;  // 16 panels
    Bbase = B + (size_t)bx * 256 * 1024;
  } else {
    const int id = blockIdx.x;                  // grid 160 = 8*20
    const int work = (id & 7) * 20 + (id >> 3); // XCD chunk of 20 works
    const int ty = work >> 2;
    if (ty >= ntile[0]) return;
    bx = work & 3;
    const int e = te[ty];
    m0 = tm[ty];
    rbeg = offs[e]; rend = offs[e + 1];
    Bbase = B + ((size_t)e * 1024 + bx * 256) * 1024;
  }

  // staging source pointers (global col pre-swizzled, rule 21)
  const int srow = td >> 3;
  const int colsw8 = ((td & 7) ^ (srow & 7)) * 8;
  const short* ap[2][2];
  const short* bp[2][2];
#pragma unroll
  for (int h = 0; h < 2; h++)
#pragma unroll
    for (int i = 0; i < 2; i++) {
      const int trow = h * 128 + i * 64 + srow;
      int grow;
      if (MODE == 0) grow = m0 + trow;
      else if (MODE == 1) grow = perm[min(rbeg + m0 + trow, rend - 1)] >> 1;
      else grow = min(rbeg + m0 + trow, rend - 1);
      ap[h][i] = A + (size_t)grow * 1024 + colsw8;
      bp[h][i] = Bbase + (size_t)trow * 1024 + colsw8;
    }

// U1: B rows 0..127 | U2: B rows 128..255 | U3: A i0-rows | U4: A i1-rows
#define SU1(t_, b_)                                                        \
  do {                                                                     \
    gl_lds16(bp[0][0] + (t_) * 64, lds + (b_) * 32768 + 16384 + td * 8);   \
    gl_lds16(bp[0][1] + (t_) * 64, lds + (b_) * 32768 + 16384 + 4096 + td * 8); \
  } while (0)
#define SU2(t_, b_)                                                        \
  do {                                                                     \
    gl_lds16(bp[1][0] + (t_) * 64, lds + (b_) * 32768 + 16384 + 8192 + td * 8); \
    gl_lds16(bp[1][1] + (t_) * 64, lds + (b_) * 32768 + 16384 + 8192 + 4096 + td * 8); \
  } while (0)
#define SU3(t_, b_)                                                        \
  do {                                                                     \
    gl_lds16(ap[0][0] + (t_) * 64, lds + (b_) * 32768 + td * 8);           \
    gl_lds16(ap[1][0] + (t_) * 64, lds + (b_) * 32768 + 8192 + td * 8);    \
  } while (0)
#define SU4(t_, b_)                                                        \
  do {                                                                     \
    gl_lds16(ap[0][1] + (t_) * 64, lds + (b_) * 32768 + 4096 + td * 8);    \
    gl_lds16(ap[1][1] + (t_) * 64, lds + (b_) * 32768 + 8192 + 4096 + td * 8); \
  } while (0)

  const int l = td & 63;
  const int wid = td >> 6;
  const int mh = wid >> 2;
  const int wn4 = wid & 3;
  const int lr = l & 15;
  const int bhsel = wn4 >> 1;
  const int bnr = (wn4 & 1) * 64;
  const int swzk0 = ((0 + (l >> 4) * 16) ^ ((l & 7) << 4)) >> 1;
  const int swzk1 = ((64 + (l >> 4) * 16) ^ ((l & 7) << 4)) >> 1;

#define LDA(mf_, swz_) (*(const bf16x8*)&Ah[(unsigned)(((mf_)*16 + lr) * 64) + (swz_)])
#define LDB(nf_, swz_) (*(const bf16x8*)&Bh[(unsigned)((bnr + (nf_)*16 + lr) * 64) + (swz_)])
#define MMROW(mf_, a_)                                                                 \
  acc[mf_][0] = __builtin_amdgcn_mfma_f32_16x16x32_bf16(a_, b0, acc[mf_][0], 0, 0, 0); \
  acc[mf_][1] = __builtin_amdgcn_mfma_f32_16x16x32_bf16(a_, b1, acc[mf_][1], 0, 0, 0); \
  acc[mf_][2] = __builtin_amdgcn_mfma_f32_16x16x32_bf16(a_, b2, acc[mf_][2], 0, 0, 0); \
  acc[mf_][3] = __builtin_amdgcn_mfma_f32_16x16x32_bf16(a_, b3, acc[mf_][3], 0, 0, 0)

#define PH_TAIL                                   \
  __builtin_amdgcn_s_barrier();                   \
  __builtin_amdgcn_s_setprio(1)
#define PH_END                                    \
  __builtin_amdgcn_s_setprio(0);                  \
  __builtin_amdgcn_s_barrier()

  f32x4 acc[8][4] = {};

  // prologue: tile 0 -> buf 0; wait U1-U3 landed (U4(0) stays in flight)
  SU1(0, 0); SU2(0, 0); SU3(0, 0); SU4(0, 0);
  asm volatile("s_waitcnt vmcnt(2)" ::: "memory");
  __builtin_amdgcn_s_barrier();

  for (int t = 0; t < 16; ++t) {
    const int p = t & 1, q = p ^ 1;
    const short* Ah = lds + p * 32768 + mh * 8192;
    const short* Bh = lds + p * 32768 + 16384 + bhsel * 8192;
    bf16x8 b0, b1, b2, b3, a0, a1, a2, a3;
    // ph1: k0 mf0-3 | issue U1,U2(t+1) | vmcnt(4) -> U4(t) (3 phases old)
    b0 = LDB(0, swzk0); b1 = LDB(1, swzk0); b2 = LDB(2, swzk0); b3 = LDB(3, swzk0);
    a0 = LDA(0, swzk0); a1 = LDA(1, swzk0); a2 = LDA(2, swzk0); a3 = LDA(3, swzk0);
    if (t < 15) {
      SU1(t + 1, q); SU2(t + 1, q);
      asm volatile("s_waitcnt vmcnt(4)" ::: "memory");
    } else {
      asm volatile("s_waitcnt vmcnt(0)" ::: "memory");
    }
    PH_TAIL;
    MMROW(0, a0); MMROW(1, a1); MMROW(2, a2); MMROW(3, a3);
    PH_END;
    // ph2: k0 mf4-7 (needs U4(t), guaranteed) | issue U3,U4(t+1)
    a0 = LDA(4, swzk0); a1 = LDA(5, swzk0); a2 = LDA(6, swzk0); a3 = LDA(7, swzk0);
    if (t < 15) { SU3(t + 1, q); SU4(t + 1, q); }
    PH_TAIL;
    MMROW(4, a0); MMROW(5, a1); MMROW(6, a2); MMROW(7, a3);
    PH_END;
    // ph3: k1 mf0-3 (no staging)
    b0 = LDB(0, swzk1); b1 = LDB(1, swzk1); b2 = LDB(2, swzk1); b3 = LDB(3, swzk1);
    a0 = LDA(0, swzk1); a1 = LDA(1, swzk1); a2 = LDA(2, swzk1); a3 = LDA(3, swzk1);
    PH_TAIL;
    MMROW(0, a0); MMROW(1, a1); MMROW(2, a2); MMROW(3, a3);
    PH_END;
    // ph4: k1 mf4-7 | vmcnt(2) -> U1-U3(t+1) (>=2 phases old), leaves U4(t+1)
    a0 = LDA(4, swzk1); a1 = LDA(5, swzk1); a2 = LDA(6, swzk1); a3 = LDA(7, swzk1);
    if (t < 15) asm volatile("s_waitcnt vmcnt(2)" ::: "memory");
    PH_TAIL;
    MMROW(4, a0); MMROW(5, a1); MMROW(6, a2); MMROW(7, a3);
    PH_END;
  }

  // ---- epilogue ----
  const int rsub = (l >> 4) * 4;
  if (MODE == 0) {
#pragma unroll
    for (int mf = 0; mf < 8; mf++)
#pragma unroll
      for (int j = 0; j < 4; j++) {
        const int row = m0 + mh * 128 + mf * 16 + rsub + j;
        short* Up = Cout + (size_t)row * HS + bx * 128 + wn4 * 32 + lr;
#pragma unroll
        for (int nfp = 0; nfp < 2; nfp++) {
          const float a = acc[mf][nfp][j];
          const float b = acc[mf][nfp + 2][j];
          Up[nfp * 16] = f2b(a / (1.f + expf(-a)) * b);
        }
      }
  } else if (MODE == 1) {
#pragma unroll
    for (int mf = 0; mf < 8; mf++)
#pragma unroll
      for (int j = 0; j < 4; j++) {
        const int gi = rbeg + m0 + mh * 128 + mf * 16 + rsub + j;
        if (gi < rend) {
          short* Cp = Cout + (size_t)gi * HE + bx * 256 + wn4 * 64 + lr;
#pragma unroll
          for (int nf = 0; nf < 4; nf++) {
            const float v = acc[mf][nf][j];
            Cp[nf * 16] = f2b(0.5f * v * (1.0f + erff(v * 0.70710678118654752f)));
          }
        }
      }
  } else {
#pragma unroll
    for (int mf = 0; mf < 8; mf++)
#pragma unroll
      for (int j = 0; j < 4; j++) {
        const int gi = rbeg + m0 + mh * 128 + mf * 16 + rsub + j;
        if (gi < rend) {
          const int slot = perm[gi];
          const float g = gates[slot];
          short* Cp = Cout + (size_t)slot * D_MODEL + bx * 256 + wn4 * 64 + lr;
#pragma unroll
          for (int nf = 0; nf < 4; nf++) Cp[nf * 16] = f2b(g * acc[mf][nf][j]);
        }
      }
  }
#undef SU1
#undef SU2
#undef SU3
#undef SU4
#undef LDA
#undef LDB
#undef MMROW
#undef PH_TAIL
#undef PH_END
}

// ---------------- G2: shared = u @ w2, fused final combine (2-phase 128²) ----
// 1D grid 256, XCD rectangle swizzle (8bx x 4my per XCD).
__global__ __launch_bounds__(256, 2) void gemm_g2(
    const short* __restrict__ A, const short* __restrict__ B,
    const short* __restrict__ yb, float* __restrict__ out) {
  __shared__ __align__(16) short As[4096];
  __shared__ __align__(16) short Bs[4096];
  const int t = threadIdx.x;
  const int id = blockIdx.x, xcd = id & 7, slot = id >> 3;
  const int tile_n = (slot & 7) * 128;              // 8 bx panels
  const int m0 = (xcd * 4 + (slot >> 3)) * 128;     // 32 my panels
  const int r = t >> 2;
  const int c8 = (t & 3) * 8;
  const short* Ap0 = A + (size_t)(m0 + r) * HS + c8;
  const short* Ap1 = A + (size_t)(m0 + 64 + r) * HS + c8;
  const short* Bp0 = B + (size_t)(tile_n + r) * HS + c8;
  const short* Bp1 = B + (size_t)(tile_n + 64 + r) * HS + c8;

  const int lane = t & 63, wv = t >> 6;
  const int wm = (wv >> 1) * 64, wn = (wv & 1) * 64;
  const int lr = lane & 15, lk = (lane >> 4) * 8;

  f32x4 acc[4][4] = {};
  for (int k0 = 0; k0 < HS; k0 += 32) {
    gl_lds16(Ap0 + k0, &As[t * 8]);
    gl_lds16(Ap1 + k0, &As[2048 + t * 8]);
    gl_lds16(Bp0 + k0, &Bs[t * 8]);
    gl_lds16(Bp1 + k0, &Bs[2048 + t * 8]);
    __syncthreads();
    bf16x8 af[4], bfr[4];
#pragma unroll
    for (int m = 0; m < 4; m++) af[m] = *(const bf16x8*)&As[(wm + m * 16 + lr) * 32 + lk];
#pragma unroll
    for (int n = 0; n < 4; n++) bfr[n] = *(const bf16x8*)&Bs[(wn + n * 16 + lr) * 32 + lk];
#pragma unroll
    for (int m = 0; m < 4; m++)
#pragma unroll
      for (int n = 0; n < 4; n++)
        acc[m][n] = __builtin_amdgcn_mfma_f32_16x16x32_bf16(af[m], bfr[n], acc[m][n], 0, 0, 0);
    __syncthreads();
  }

  const int rq = (lane >> 4) * 4;
  const float inv3 = 1.0f / 3.0f;
#pragma unroll
  for (int m = 0; m < 4; m++) {
#pragma unroll
    for (int j = 0; j < 4; j++) {
      const int tok = m0 + wm + m * 16 + rq + j;
      const int colb = tile_n + wn + lr;
      const short* y0p = yb + (size_t)(tok * 2) * D_MODEL + colb;
      const short* y1p = yb + (size_t)(tok * 2 + 1) * D_MODEL + colb;
      float* Op = out + (size_t)tok * D_MODEL + colb;
#pragma unroll
      for (int n = 0; n < 4; n++) {
        Op[n * 16] = (acc[m][n][j] + b2f(y0p[n * 16]) + b2f(y1p[n * 16])) * inv3;
      }
    }
  }
}

// ---------------- launch ----------------
extern "C" void kernel_launch(void* const* d_in, const int* in_sizes, int n_in,
                              void* d_out, int out_size, void* d_ws, size_t ws_size,
                              hipStream_t stream) {
  const float* x = (const float*)d_in[0];
  const float* temb = (const float*)d_in[1];
  const float* rw = (const float*)d_in[2];
  const float* rbias = (const float*)d_in[3];
  const float* w1 = (const float*)d_in[4];
  const float* w3 = (const float*)d_in[5];
  const float* w2 = (const float*)d_in[6];
  const float* W1e = (const float*)d_in[7];
  const float* W2e = (const float*)d_in[8];
  float* out = (float*)d_out;

  const size_t MB = 1ull << 20;
  char* w = (char*)d_ws;
  short* xb    = (short*)(w + 0 * MB);    // 8 MB  [4096][1024]
  short* w13I  = (short*)(w + 8 * MB);    // 8 MB  [4096][1024] interleaved w1/w3
  short* w2T   = (short*)(w + 16 * MB);   // 4 MB  [1024][2048]
  short* W1eT  = (short*)(w + 20 * MB);   // 16 MB [8][1024][1024]
  short* W2eT  = (short*)(w + 36 * MB);   // 16 MB [8][1024][1024]
  short* ubuf  = (short*)(w + 52 * MB);   // 16 MB [4096][2048]
  short* hexpb = (short*)(w + 68 * MB);   // 16 MB [8192][1024]
  short* yb    = (short*)(w + 84 * MB);   // 16 MB [8192][1024] gated bf16
  float* gates = (float*)(w + 100 * MB);  // 32 KB
  int* topk    = (int*)(w + 100 * MB + 32 * 1024);
  int* perm    = (int*)(w + 100 * MB + 64 * 1024);
  int* meta    = (int*)(w + 100 * MB + 96 * 1024);
  int* offs    = meta;           // 9 ints
  int* te      = meta + 16;      // <=40
  int* tm      = meta + 128;     // <=40
  int* ntile   = meta + 256;     // 1

  hipFuncSetAttribute((const void*)&moe_gemm_8ph<0>,
                      hipFuncAttributeMaxDynamicSharedMemorySize, 131072);
  hipFuncSetAttribute((const void*)&moe_gemm_8ph<1>,
                      hipFuncAttributeMaxDynamicSharedMemorySize, 131072);
  hipFuncSetAttribute((const void*)&moe_gemm_8ph<2>,
                      hipFuncAttributeMaxDynamicSharedMemorySize, 131072);

  // prep (cvt_x now fused into router)
  tr_w13<<<dim3(HS / 64, D_MODEL / 64, 2), 256, 0, stream>>>(w1, w3, w13I);
  tr_w2<<<dim3(D_MODEL / 64, HS / 64, 1), 256, 0, stream>>>(w2, w2T);
  tr_exp<<<dim3(16, 16, 16), 256, 0, stream>>>(W1e, W2e, W1eT, W2eT);
  router_kernel<<<NTOK / 4, 256, 0, stream>>>(x, temb, rw, rbias, xb, topk, gates);
  group_kernel<<<1, 1024, 0, stream>>>(topk, perm, offs, te, tm, ntile);

  // G1: u = silu(x@w1)*(x@w3)  (256 blocks, XCD rectangles)
  moe_gemm_8ph<0><<<256, 512, 131072, stream>>>(xb, w13I, ubuf, nullptr, nullptr,
                                                nullptr, nullptr, nullptr, nullptr);

  // routed experts: BM=256 compact, <=160 blocks -> single dispatch wave
  moe_gemm_8ph<1><<<160, 512, 131072, stream>>>(xb, W1eT, hexpb, perm, offs,
                                                gates, te, tm, ntile);
  moe_gemm_8ph<2><<<160, 512, 131072, stream>>>(hexpb, W2eT, yb, perm, offs,
                                                gates, te, tm, ntile);

  // shared down-proj + final combine
  gemm_g2<<<256, 256, 0, stream>>>(ubuf, w2T, yb, out);
}

// Round 11
// 225.694 us; speedup vs baseline: 1.1441x; 1.0471x over previous
//
#include <hip/hip_runtime.h>
#include <hip/hip_bf16.h>
#include <math.h>

#define D_MODEL 1024
#define HS 2048
#define HE 1024
#define NEXP 8
#define NTOK 4096
#define NSLOT 8192

typedef __attribute__((ext_vector_type(4))) float f32x4;
typedef __attribute__((ext_vector_type(8))) short bf16x8;

__device__ __forceinline__ short f2b(float f) {
  __hip_bfloat16 h = __float2bfloat16(f);
  return *reinterpret_cast<short*>(&h);
}
__device__ __forceinline__ float b2f(short s) {
  return __bfloat162float(*reinterpret_cast<__hip_bfloat16*>(&s));
}

__device__ __forceinline__ void gl_lds16(const short* g, short* l) {
  __builtin_amdgcn_global_load_lds(
      (const __attribute__((address_space(1))) void*)g,
      (__attribute__((address_space(3))) void*)l, 16, 0, 0);
}

// shared transpose tile body: in [R][C] f32 -> out bf16 transposed.
// rmap 0: plain [C][R]; rmap 1/2: w13I interleave out_row=(c>>5)*64+(rmap==2?32:0)+(c&31)
__device__ __forceinline__ void tr_tile(const float* __restrict__ in,
                                        short* __restrict__ out, int R, int C,
                                        int bx, int by, int bz, int rmap,
                                        float (*tile)[69], int t) {
  const int c0 = bx * 64;
  const int r0 = by * 64;
  const size_t bo = (size_t)bz * R * C;
  const int lr = t >> 4;
  const int lc4 = (t & 15) * 4;
#pragma unroll
  for (int i = 0; i < 4; i++) {
    const float4 v = *(const float4*)&in[bo + (size_t)(r0 + lr + i * 16) * C + c0 + lc4];
    tile[lc4 + 0][lr + i * 16] = v.x;
    tile[lc4 + 1][lr + i * 16] = v.y;
    tile[lc4 + 2][lr + i * 16] = v.z;
    tile[lc4 + 3][lr + i * 16] = v.w;
  }
  __syncthreads();
#pragma unroll
  for (int i = 0; i < 4; i++) {
    const int oc = (t >> 4) + i * 16;
    const int or4 = (t & 15) * 4;
    short4 o;
    o.x = f2b(tile[oc][or4 + 0]);
    o.y = f2b(tile[oc][or4 + 1]);
    o.z = f2b(tile[oc][or4 + 2]);
    o.w = f2b(tile[oc][or4 + 3]);
    const int c = c0 + oc;
    size_t orow;
    if (rmap == 0) orow = bo + (size_t)c * R;
    else orow = (size_t)((c >> 5) * 64 + (rmap == 2 ? 32 : 0) + (c & 31)) * R;
    *(short4*)&out[orow + r0 + or4] = o;
  }
}

__global__ __launch_bounds__(256) void tr_w13(const float* __restrict__ w1,
                                              const float* __restrict__ w3,
                                              short* __restrict__ w13I) {
  __shared__ float tile[64][69];
  const int z = blockIdx.z;
  tr_tile(z ? w3 : w1, w13I, D_MODEL, HS, blockIdx.x, blockIdx.y, 0, z ? 2 : 1,
          tile, threadIdx.x);
}

__global__ __launch_bounds__(256) void tr_w2(const float* __restrict__ w2,
                                             short* __restrict__ w2T) {
  __shared__ float tile[64][69];
  tr_tile(w2, w2T, HS, D_MODEL, blockIdx.x, blockIdx.y, 0, 0, tile, threadIdx.x);
}

__global__ __launch_bounds__(256) void tr_exp(const float* __restrict__ W1e,
                                              const float* __restrict__ W2e,
                                              short* __restrict__ W1eT,
                                              short* __restrict__ W2eT) {
  __shared__ float tile[64][69];
  const int z = blockIdx.z;
  if (z < 8)
    tr_tile(W1e, W1eT, D_MODEL, HE, blockIdx.x, blockIdx.y, z, 0, tile, threadIdx.x);
  else
    tr_tile(W2e, W2eT, HE, D_MODEL, blockIdx.x, blockIdx.y, z - 8, 0, tile, threadIdx.x);
}

// ------- router + x->bf16 convert fused -------
__global__ __launch_bounds__(256) void router_kernel(
    const float* __restrict__ x, const float* __restrict__ temb,
    const float* __restrict__ rw, const float* __restrict__ rbias,
    short* __restrict__ xb, int* __restrict__ topk, float* __restrict__ gates) {
  const int t = (blockIdx.x * 256 + threadIdx.x) >> 6;
  const int lane = threadIdx.x & 63;
  const float* xr = x + (size_t)t * D_MODEL;
  const float* tr = temb + (size_t)(t >> 10) * D_MODEL;  // T=1024
  float acc[NEXP] = {};
#pragma unroll
  for (int i = 0; i < 4; i++) {
    const int j = i * 256 + lane * 4;
    const float4 xv = *(const float4*)&xr[j];
    const float4 tv = *(const float4*)&tr[j];
    short4 o;
    o.x = f2b(xv.x); o.y = f2b(xv.y); o.z = f2b(xv.z); o.w = f2b(xv.w);
    *(short4*)&xb[(size_t)t * D_MODEL + j] = o;
    const float* wx = rw + (size_t)j * NEXP;
    const float* wt = rw + (size_t)(D_MODEL + j) * NEXP;
    const float xa[4] = {xv.x, xv.y, xv.z, xv.w};
    const float ta[4] = {tv.x, tv.y, tv.z, tv.w};
#pragma unroll
    for (int u = 0; u < 4; u++)
#pragma unroll
      for (int e = 0; e < NEXP; e++)
        acc[e] += xa[u] * wx[u * NEXP + e] + ta[u] * wt[u * NEXP + e];
  }
#pragma unroll
  for (int off = 32; off; off >>= 1)
#pragma unroll
    for (int e = 0; e < NEXP; e++) acc[e] += __shfl_xor(acc[e], off);
  if (lane == 0) {
    float s[NEXP], sel[NEXP];
#pragma unroll
    for (int e = 0; e < NEXP; e++) {
      s[e] = 1.f / (1.f + expf(-acc[e]));
      sel[e] = s[e] + rbias[e];
    }
    int i0 = 0;
#pragma unroll
    for (int e = 1; e < NEXP; e++) if (sel[e] > sel[i0]) i0 = e;
    int i1 = (i0 == 0) ? 1 : 0;
#pragma unroll
    for (int e = 0; e < NEXP; e++) if (e != i0 && sel[e] > sel[i1]) i1 = e;
    float s0 = s[i0], s1 = s[i1], den = s0 + s1;
    float g0, g1;
    if (den > 1e-9f) { g0 = s0 / (den + 1e-9f); g1 = s1 / (den + 1e-9f); }
    else { g0 = 0.5f; g1 = 0.5f; }
    topk[t * 2] = i0; topk[t * 2 + 1] = i1;
    gates[t * 2] = g0; gates[t * 2 + 1] = g1;
  }
}

// ------- grouping: hist + scan + fill + BM=256 tile table in one block ------
__global__ __launch_bounds__(1024) void group_kernel(const int* __restrict__ topk,
                                                     int* __restrict__ perm,
                                                     int* __restrict__ offs,
                                                     int* __restrict__ te,
                                                     int* __restrict__ tm,
                                                     int* __restrict__ ntile) {
  __shared__ int cnt[NEXP], cur[NEXP];
  const int t = threadIdx.x;
  if (t < NEXP) cnt[t] = 0;
  __syncthreads();
  int mye[8];
#pragma unroll
  for (int i = 0; i < 8; i++) {
    mye[i] = topk[i * 1024 + t];
    atomicAdd(&cnt[mye[i]], 1);
  }
  __syncthreads();
  if (t == 0) {
    int a = 0;
    for (int e = 0; e < NEXP; e++) { offs[e] = a; cur[e] = a; a += cnt[e]; }
    offs[NEXP] = a;
    int nt = 0;
    for (int e = 0; e < NEXP; e++)
      for (int m0 = 0; m0 < cnt[e]; m0 += 256) { te[nt] = e; tm[nt] = m0; nt++; }
    ntile[0] = nt;  // <= 40
  }
  __syncthreads();
#pragma unroll
  for (int i = 0; i < 8; i++) {
    int pos = atomicAdd(&cur[mye[i]], 1);
    perm[pos] = i * 1024 + t;
  }
}

// ====== unified 256x256 BK=64 COUNTED-2-BARRIER GEMM (R11 template) ======
// Per K-tile: {stage ALL 8 loads of t+1 -> q; vmcnt(8) [drains exactly tile
// t's 8, counted]; s_barrier [publish]; reads+MFMA compiler-scheduled with
// fine lgkmcnt; sched_barrier(0); s_barrier [certify reads done -> q safe]}.
// 2 barriers/K-tile (was 8). End-barrier of t-1 makes stage(t+1->q) race-free.
template <int MODE>
__global__ __launch_bounds__(512, 1) void moe_gemm_ct(
    const short* __restrict__ A, const short* __restrict__ B, short* __restrict__ Cout,
    const int* __restrict__ perm, const int* __restrict__ offs,
    const float* __restrict__ gates, const int* __restrict__ te,
    const int* __restrict__ tm, const int* __restrict__ ntile) {
  extern __shared__ short lds[];
  const int td = threadIdx.x;
  int bx, m0, rbeg = 0, rend = 0;
  const short* Bbase;
  if (MODE == 0) {
    const int id = blockIdx.x, xcd = id & 7, slot = id >> 3;
    bx = (xcd & 3) * 4 + (slot & 3);            // 0..15
    m0 = ((xcd >> 2) * 8 + (slot >> 2)) * 256;  // 16 panels
    Bbase = B + (size_t)bx * 256 * 1024;
  } else {
    const int id = blockIdx.x;                  // grid 160 = 8*20
    const int work = (id & 7) * 20 + (id >> 3); // XCD chunk of 20 works
    const int ty = work >> 2;
    if (ty >= ntile[0]) return;
    bx = work & 3;
    const int e = te[ty];
    m0 = tm[ty];
    rbeg = offs[e]; rend = offs[e + 1];
    Bbase = B + ((size_t)e * 1024 + bx * 256) * 1024;
  }

  const int srow = td >> 3;
  const int colsw8 = ((td & 7) ^ (srow & 7)) * 8;
  const short* ap[2][2];
  const short* bp[2][2];
#pragma unroll
  for (int h = 0; h < 2; h++)
#pragma unroll
    for (int i = 0; i < 2; i++) {
      const int trow = h * 128 + i * 64 + srow;
      int grow;
      if (MODE == 0) grow = m0 + trow;
      else if (MODE == 1) grow = perm[min(rbeg + m0 + trow, rend - 1)] >> 1;
      else grow = min(rbeg + m0 + trow, rend - 1);
      ap[h][i] = A + (size_t)grow * 1024 + colsw8;
      bp[h][i] = Bbase + (size_t)trow * 1024 + colsw8;
    }

#define STAGE_ALL(t_, b_)                                                       \
  do {                                                                          \
    gl_lds16(bp[0][0] + (t_) * 64, lds + (b_) * 32768 + 16384 + td * 8);        \
    gl_lds16(bp[0][1] + (t_) * 64, lds + (b_) * 32768 + 16384 + 4096 + td * 8); \
    gl_lds16(bp[1][0] + (t_) * 64, lds + (b_) * 32768 + 16384 + 8192 + td * 8); \
    gl_lds16(bp[1][1] + (t_) * 64, lds + (b_) * 32768 + 16384 + 12288 + td * 8);\
    gl_lds16(ap[0][0] + (t_) * 64, lds + (b_) * 32768 + td * 8);                \
    gl_lds16(ap[0][1] + (t_) * 64, lds + (b_) * 32768 + 4096 + td * 8);         \
    gl_lds16(ap[1][0] + (t_) * 64, lds + (b_) * 32768 + 8192 + td * 8);         \
    gl_lds16(ap[1][1] + (t_) * 64, lds + (b_) * 32768 + 12288 + td * 8);        \
  } while (0)

  const int l = td & 63;
  const int wid = td >> 6;
  const int mh = wid >> 2;
  const int wn4 = wid & 3;
  const int lr = l & 15;
  const int bhsel = wn4 >> 1;
  const int bnr = (wn4 & 1) * 64;
  const int swzk0 = ((0 + (l >> 4) * 16) ^ ((l & 7) << 4)) >> 1;
  const int swzk1 = ((64 + (l >> 4) * 16) ^ ((l & 7) << 4)) >> 1;

#define LDA(mf_, swz_) (*(const bf16x8*)&Ah[(unsigned)(((mf_)*16 + lr) * 64) + (swz_)])
#define LDB(nf_, swz_) (*(const bf16x8*)&Bh[(unsigned)((bnr + (nf_)*16 + lr) * 64) + (swz_)])
#define MMROW(mf_, a_)                                                                 \
  acc[mf_][0] = __builtin_amdgcn_mfma_f32_16x16x32_bf16(a_, b0, acc[mf_][0], 0, 0, 0); \
  acc[mf_][1] = __builtin_amdgcn_mfma_f32_16x16x32_bf16(a_, b1, acc[mf_][1], 0, 0, 0); \
  acc[mf_][2] = __builtin_amdgcn_mfma_f32_16x16x32_bf16(a_, b2, acc[mf_][2], 0, 0, 0); \
  acc[mf_][3] = __builtin_amdgcn_mfma_f32_16x16x32_bf16(a_, b3, acc[mf_][3], 0, 0, 0)

  f32x4 acc[8][4] = {};

  // prologue: tile 0 -> buf 0 (8 loads in flight)
  STAGE_ALL(0, 0);

  for (int t = 0; t < 16; ++t) {
    const int p = t & 1, q = p ^ 1;
    const short* Ah = lds + p * 32768 + mh * 8192;
    const short* Bh = lds + p * 32768 + 16384 + bhsel * 8192;
    if (t < 15) {
      STAGE_ALL(t + 1, q);  // q read last at t-1; end-barrier(t-1) certifies
      asm volatile("s_waitcnt vmcnt(8)" ::: "memory");  // drains tile t's 8
    } else {
      asm volatile("s_waitcnt vmcnt(0)" ::: "memory");
    }
    __builtin_amdgcn_s_barrier();  // publish tile t
    {
      bf16x8 b0, b1, b2, b3, a0, a1, a2, a3;
      b0 = LDB(0, swzk0); b1 = LDB(1, swzk0); b2 = LDB(2, swzk0); b3 = LDB(3, swzk0);
      a0 = LDA(0, swzk0); a1 = LDA(1, swzk0); a2 = LDA(2, swzk0); a3 = LDA(3, swzk0);
      __builtin_amdgcn_s_setprio(1);
      MMROW(0, a0); MMROW(1, a1); MMROW(2, a2); MMROW(3, a3);
      __builtin_amdgcn_s_setprio(0);
      a0 = LDA(4, swzk0); a1 = LDA(5, swzk0); a2 = LDA(6, swzk0); a3 = LDA(7, swzk0);
      __builtin_amdgcn_s_setprio(1);
      MMROW(4, a0); MMROW(5, a1); MMROW(6, a2); MMROW(7, a3);
      __builtin_amdgcn_s_setprio(0);
      b0 = LDB(0, swzk1); b1 = LDB(1, swzk1); b2 = LDB(2, swzk1); b3 = LDB(3, swzk1);
      a0 = LDA(0, swzk1); a1 = LDA(1, swzk1); a2 = LDA(2, swzk1); a3 = LDA(3, swzk1);
      __builtin_amdgcn_s_setprio(1);
      MMROW(0, a0); MMROW(1, a1); MMROW(2, a2); MMROW(3, a3);
      __builtin_amdgcn_s_setprio(0);
      a0 = LDA(4, swzk1); a1 = LDA(5, swzk1); a2 = LDA(6, swzk1); a3 = LDA(7, swzk1);
      __builtin_amdgcn_s_setprio(1);
      MMROW(4, a0); MMROW(5, a1); MMROW(6, a2); MMROW(7, a3);
      __builtin_amdgcn_s_setprio(0);
    }
    __builtin_amdgcn_sched_barrier(0);  // keep reads above the end barrier
    __builtin_amdgcn_s_barrier();       // reads(t) done -> q stageable at t+1
  }

  // ---- epilogue ----
  const int rsub = (l >> 4) * 4;
  if (MODE == 0) {
#pragma unroll
    for (int mf = 0; mf < 8; mf++)
#pragma unroll
      for (int j = 0; j < 4; j++) {
        const int row = m0 + mh * 128 + mf * 16 + rsub + j;
        short* Up = Cout + (size_t)row * HS + bx * 128 + wn4 * 32 + lr;
#pragma unroll
        for (int nfp = 0; nfp < 2; nfp++) {
          const float a = acc[mf][nfp][j];
          const float b = acc[mf][nfp + 2][j];
          Up[nfp * 16] = f2b(a / (1.f + expf(-a)) * b);
        }
      }
  } else if (MODE == 1) {
#pragma unroll
    for (int mf = 0; mf < 8; mf++)
#pragma unroll
      for (int j = 0; j < 4; j++) {
        const int gi = rbeg + m0 + mh * 128 + mf * 16 + rsub + j;
        if (gi < rend) {
          short* Cp = Cout + (size_t)gi * HE + bx * 256 + wn4 * 64 + lr;
#pragma unroll
          for (int nf = 0; nf < 4; nf++) {
            const float v = acc[mf][nf][j];
            Cp[nf * 16] = f2b(0.5f * v * (1.0f + erff(v * 0.70710678118654752f)));
          }
        }
      }
  } else {
#pragma unroll
    for (int mf = 0; mf < 8; mf++)
#pragma unroll
      for (int j = 0; j < 4; j++) {
        const int gi = rbeg + m0 + mh * 128 + mf * 16 + rsub + j;
        if (gi < rend) {
          const int slot = perm[gi];
          const float g = gates[slot];
          short* Cp = Cout + (size_t)slot * D_MODEL + bx * 256 + wn4 * 64 + lr;
#pragma unroll
          for (int nf = 0; nf < 4; nf++) Cp[nf * 16] = f2b(g * acc[mf][nf][j]);
        }
      }
  }
#undef STAGE_ALL
#undef LDA
#undef LDB
#undef MMROW
}

// ====== G2: u @ w2 + combine, 128² BK=64 counted-2-barrier double-buffer ======
// 4 waves (2x2), LDS 64KB (2 buf x {A 128x64 | B 128x64}) -> 2 blocks/CU.
// Same counted schedule as moe_gemm_ct. K=2048 -> 32 K-tiles.
__global__ __launch_bounds__(256, 2) void gemm_g2_ct(
    const short* __restrict__ A, const short* __restrict__ B,
    const short* __restrict__ yb, float* __restrict__ out) {
  extern __shared__ short lds[];
  const int td = threadIdx.x;
  const int id = blockIdx.x, xcd = id & 7, slot = id >> 3;
  const int tile_n = (slot & 7) * 128;           // 8 n panels
  const int m0 = (xcd * 4 + (slot >> 3)) * 128;  // 32 m panels

  const int srow = td >> 3;  // 0..31
  const int colsw8 = ((td & 7) ^ (srow & 7)) * 8;
  const short* ap[4];
  const short* bp[4];
#pragma unroll
  for (int u = 0; u < 4; u++) {
    ap[u] = A + (size_t)(m0 + u * 32 + srow) * HS + colsw8;
    bp[u] = B + (size_t)(tile_n + u * 32 + srow) * HS + colsw8;
  }

#define STAGE_ALL2(t_, b_)                                                 \
  do {                                                                     \
    gl_lds16(ap[0] + (t_) * 64, lds + (b_) * 16384 + td * 8);              \
    gl_lds16(ap[1] + (t_) * 64, lds + (b_) * 16384 + 2048 + td * 8);       \
    gl_lds16(ap[2] + (t_) * 64, lds + (b_) * 16384 + 4096 + td * 8);       \
    gl_lds16(ap[3] + (t_) * 64, lds + (b_) * 16384 + 6144 + td * 8);       \
    gl_lds16(bp[0] + (t_) * 64, lds + (b_) * 16384 + 8192 + td * 8);       \
    gl_lds16(bp[1] + (t_) * 64, lds + (b_) * 16384 + 10240 + td * 8);      \
    gl_lds16(bp[2] + (t_) * 64, lds + (b_) * 16384 + 12288 + td * 8);      \
    gl_lds16(bp[3] + (t_) * 64, lds + (b_) * 16384 + 14336 + td * 8);      \
  } while (0)

  const int l = td & 63;
  const int wv = td >> 6;
  const int wm = (wv >> 1) * 64, wn = (wv & 1) * 64;
  const int lr = l & 15;
  const int swzk0 = ((0 + (l >> 4) * 16) ^ ((l & 7) << 4)) >> 1;
  const int swzk1 = ((64 + (l >> 4) * 16) ^ ((l & 7) << 4)) >> 1;

#define LDA2(mf_, swz_) (*(const bf16x8*)&Ah[(unsigned)(((mf_)*16 + lr) * 64) + (swz_)])
#define LDB2(nf_, swz_) (*(const bf16x8*)&Bh[(unsigned)(((nf_)*16 + lr) * 64) + (swz_)])
#define MMROW2(mf_, a_)                                                                \
  acc[mf_][0] = __builtin_amdgcn_mfma_f32_16x16x32_bf16(a_, b0, acc[mf_][0], 0, 0, 0); \
  acc[mf_][1] = __builtin_amdgcn_mfma_f32_16x16x32_bf16(a_, b1, acc[mf_][1], 0, 0, 0); \
  acc[mf_][2] = __builtin_amdgcn_mfma_f32_16x16x32_bf16(a_, b2, acc[mf_][2], 0, 0, 0); \
  acc[mf_][3] = __builtin_amdgcn_mfma_f32_16x16x32_bf16(a_, b3, acc[mf_][3], 0, 0, 0)

  f32x4 acc[4][4] = {};

  STAGE_ALL2(0, 0);
  for (int t = 0; t < 32; ++t) {
    const int p = t & 1, q = p ^ 1;
    const short* Ah = lds + p * 16384 + wm * 64;
    const short* Bh = lds + p * 16384 + 8192 + wn * 64;
    if (t < 31) {
      STAGE_ALL2(t + 1, q);
      asm volatile("s_waitcnt vmcnt(8)" ::: "memory");
    } else {
      asm volatile("s_waitcnt vmcnt(0)" ::: "memory");
    }
    __builtin_amdgcn_s_barrier();
    {
      bf16x8 b0, b1, b2, b3, a0, a1, a2, a3;
      b0 = LDB2(0, swzk0); b1 = LDB2(1, swzk0); b2 = LDB2(2, swzk0); b3 = LDB2(3, swzk0);
      a0 = LDA2(0, swzk0); a1 = LDA2(1, swzk0); a2 = LDA2(2, swzk0); a3 = LDA2(3, swzk0);
      __builtin_amdgcn_s_setprio(1);
      MMROW2(0, a0); MMROW2(1, a1); MMROW2(2, a2); MMROW2(3, a3);
      __builtin_amdgcn_s_setprio(0);
      b0 = LDB2(0, swzk1); b1 = LDB2(1, swzk1); b2 = LDB2(2, swzk1); b3 = LDB2(3, swzk1);
      a0 = LDA2(0, swzk1); a1 = LDA2(1, swzk1); a2 = LDA2(2, swzk1); a3 = LDA2(3, swzk1);
      __builtin_amdgcn_s_setprio(1);
      MMROW2(0, a0); MMROW2(1, a1); MMROW2(2, a2); MMROW2(3, a3);
      __builtin_amdgcn_s_setprio(0);
    }
    __builtin_amdgcn_sched_barrier(0);
    __builtin_amdgcn_s_barrier();
  }

  const int rq = (l >> 4) * 4;
  const float inv3 = 1.0f / 3.0f;
#pragma unroll
  for (int m = 0; m < 4; m++) {
#pragma unroll
    for (int j = 0; j < 4; j++) {
      const int tok = m0 + wm + m * 16 + rq + j;
      const int colb = tile_n + wn + lr;
      const short* y0p = yb + (size_t)(tok * 2) * D_MODEL + colb;
      const short* y1p = yb + (size_t)(tok * 2 + 1) * D_MODEL + colb;
      float* Op = out + (size_t)tok * D_MODEL + colb;
#pragma unroll
      for (int n = 0; n < 4; n++) {
        Op[n * 16] = (acc[m][n][j] + b2f(y0p[n * 16]) + b2f(y1p[n * 16])) * inv3;
      }
    }
  }
#undef STAGE_ALL2
#undef LDA2
#undef LDB2
#undef MMROW2
}

// ---------------- launch ----------------
extern "C" void kernel_launch(void* const* d_in, const int* in_sizes, int n_in,
                              void* d_out, int out_size, void* d_ws, size_t ws_size,
                              hipStream_t stream) {
  const float* x = (const float*)d_in[0];
  const float* temb = (const float*)d_in[1];
  const float* rw = (const float*)d_in[2];
  const float* rbias = (const float*)d_in[3];
  const float* w1 = (const float*)d_in[4];
  const float* w3 = (const float*)d_in[5];
  const float* w2 = (const float*)d_in[6];
  const float* W1e = (const float*)d_in[7];
  const float* W2e = (const float*)d_in[8];
  float* out = (float*)d_out;

  const size_t MB = 1ull << 20;
  char* w = (char*)d_ws;
  short* xb    = (short*)(w + 0 * MB);    // 8 MB  [4096][1024]
  short* w13I  = (short*)(w + 8 * MB);    // 8 MB  [4096][1024] interleaved w1/w3
  short* w2T   = (short*)(w + 16 * MB);   // 4 MB  [1024][2048]
  short* W1eT  = (short*)(w + 20 * MB);   // 16 MB [8][1024][1024]
  short* W2eT  = (short*)(w + 36 * MB);   // 16 MB [8][1024][1024]
  short* ubuf  = (short*)(w + 52 * MB);   // 16 MB [4096][2048]
  short* hexpb = (short*)(w + 68 * MB);   // 16 MB [8192][1024]
  short* yb    = (short*)(w + 84 * MB);   // 16 MB [8192][1024] gated bf16
  float* gates = (float*)(w + 100 * MB);  // 32 KB
  int* topk    = (int*)(w + 100 * MB + 32 * 1024);
  int* perm    = (int*)(w + 100 * MB + 64 * 1024);
  int* meta    = (int*)(w + 100 * MB + 96 * 1024);
  int* offs    = meta;           // 9 ints
  int* te      = meta + 16;      // <=40
  int* tm      = meta + 128;     // <=40
  int* ntile   = meta + 256;     // 1

  hipFuncSetAttribute((const void*)&moe_gemm_ct<0>,
                      hipFuncAttributeMaxDynamicSharedMemorySize, 131072);
  hipFuncSetAttribute((const void*)&moe_gemm_ct<1>,
                      hipFuncAttributeMaxDynamicSharedMemorySize, 131072);
  hipFuncSetAttribute((const void*)&moe_gemm_ct<2>,
                      hipFuncAttributeMaxDynamicSharedMemorySize, 131072);
  hipFuncSetAttribute((const void*)&gemm_g2_ct,
                      hipFuncAttributeMaxDynamicSharedMemorySize, 65536);

  // prep
  tr_w13<<<dim3(HS / 64, D_MODEL / 64, 2), 256, 0, stream>>>(w1, w3, w13I);
  tr_w2<<<dim3(D_MODEL / 64, HS / 64, 1), 256, 0, stream>>>(w2, w2T);
  tr_exp<<<dim3(16, 16, 16), 256, 0, stream>>>(W1e, W2e, W1eT, W2eT);
  router_kernel<<<NTOK / 4, 256, 0, stream>>>(x, temb, rw, rbias, xb, topk, gates);
  group_kernel<<<1, 1024, 0, stream>>>(topk, perm, offs, te, tm, ntile);

  // G1: u = silu(x@w1)*(x@w3)  (256 blocks, XCD rectangles)
  moe_gemm_ct<0><<<256, 512, 131072, stream>>>(xb, w13I, ubuf, nullptr, nullptr,
                                               nullptr, nullptr, nullptr, nullptr);

  // routed experts: BM=256 compact, <=160 blocks -> single dispatch wave
  moe_gemm_ct<1><<<160, 512, 131072, stream>>>(xb, W1eT, hexpb, perm, offs,
                                               gates, te, tm, ntile);
  moe_gemm_ct<2><<<160, 512, 131072, stream>>>(hexpb, W2eT, yb, perm, offs,
                                               gates, te, tm, ntile);

  // shared down-proj + final combine (counted double-buffer, 2 blocks/CU)
  gemm_g2_ct<<<256, 256, 65536, stream>>>(ubuf, w2T, yb, out);
}